// Round 1
// baseline (2310.893 us; speedup 1.0000x reference)
//
#include <hip/hip_runtime.h>
#include <hip/hip_bf16.h>

#define N_NODES 100000
#define N_EDGES 1600000
#define DH 128

// ---------------------------------------------------------------------------
// Edge-index width detection: values < 2^17, so if buffer is int64 every odd
// 32-bit word (little-endian high half) of the first 1024 entries is zero.
// ---------------------------------------------------------------------------
__global__ void detect_kernel(const unsigned* __restrict__ e, int* __restrict__ flag) {
    __shared__ int nz;
    if (threadIdx.x == 0) nz = 0;
    __syncthreads();
    int local = 0;
    for (int i = threadIdx.x; i < 1024; i += blockDim.x)
        if (e[2 * i + 1] != 0) local = 1;
    if (local) atomicOr(&nz, 1);
    __syncthreads();
    if (threadIdx.x == 0) *flag = (nz == 0) ? 1 : 0;
}

__device__ __forceinline__ int edge_at(const unsigned* __restrict__ e, long idx, int is64) {
    return (int)(is64 ? e[2 * idx] : e[idx]);
}

__global__ void hist_kernel(const unsigned* __restrict__ e, const int* __restrict__ flag,
                            int* __restrict__ counts) {
    int i = blockIdx.x * blockDim.x + threadIdx.x;
    if (i >= N_EDGES) return;
    int is64 = *flag;
    int d = edge_at(e, (long)N_EDGES + i, is64);
    atomicAdd(&counts[d], 1);
}

// ---- 2-level exclusive scan over counts -> row_ptr (+ deg_inv, cursor) ----
__global__ void scan1_kernel(const int* __restrict__ counts, int* __restrict__ blockSums) {
    __shared__ int red[256];
    int base = blockIdx.x * 1024;
    int sum = 0;
    for (int i = threadIdx.x; i < 1024; i += 256) {
        int idx = base + i;
        sum += (idx < N_NODES) ? counts[idx] : 0;
    }
    red[threadIdx.x] = sum;
    __syncthreads();
    for (int s = 128; s > 0; s >>= 1) {
        if (threadIdx.x < s) red[threadIdx.x] += red[threadIdx.x + s];
        __syncthreads();
    }
    if (threadIdx.x == 0) blockSums[blockIdx.x] = red[0];
}

__global__ void scan2_kernel(int* __restrict__ blockSums, int nb, int* __restrict__ row_ptr) {
    // single thread: 98 elements, trivial
    int run = 0;
    for (int i = 0; i < nb; ++i) { int v = blockSums[i]; blockSums[i] = run; run += v; }
    row_ptr[N_NODES] = run;
}

__global__ void scan3_kernel(const int* __restrict__ counts, const int* __restrict__ blockSums,
                             int* __restrict__ row_ptr, int* __restrict__ cursor,
                             float* __restrict__ deg_inv) {
    __shared__ int lds[256];
    int base = blockIdx.x * 1024;
    int t = threadIdx.x;
    int v[4];
    int s = 0;
    for (int i = 0; i < 4; ++i) {
        int idx = base + t * 4 + i;
        v[i] = (idx < N_NODES) ? counts[idx] : 0;
        s += v[i];
    }
    lds[t] = s;
    __syncthreads();
    for (int off = 1; off < 256; off <<= 1) {
        int add = (t >= off) ? lds[t - off] : 0;
        __syncthreads();
        lds[t] += add;
        __syncthreads();
    }
    int excl = lds[t] - s + blockSums[blockIdx.x];
    for (int i = 0; i < 4; ++i) {
        int idx = base + t * 4 + i;
        if (idx < N_NODES) {
            row_ptr[idx] = excl;
            cursor[idx]  = excl;
            deg_inv[idx] = 1.0f / fmaxf((float)v[i], 1.0f);
            excl += v[i];
        }
    }
}

__global__ void fill_kernel(const unsigned* __restrict__ e, const int* __restrict__ flag,
                            int* __restrict__ cursor, int* __restrict__ csr_src) {
    int i = blockIdx.x * blockDim.x + threadIdx.x;
    if (i >= N_EDGES) return;
    int is64 = *flag;
    int s = edge_at(e, (long)i, is64);
    int d = edge_at(e, (long)N_EDGES + i, is64);
    int pos = atomicAdd(&cursor[d], 1);
    csr_src[pos] = s;
}

// ---------------------------------------------------------------------------
// Fused per-layer GEMM: y = x @ [W_lin | W_film | W_skip | W_fskip]  (768 cols)
// Writes h (bf16), beta|gamma (bf16, +b_film), and out = relu(gamma_s*skip+beta_s)
// Block: 16 nodes x 768 cols, 256 threads, each thread 3 cols x 16 nodes.
// ---------------------------------------------------------------------------
__global__ __launch_bounds__(256, 2) void gemm_kernel(
    const float* __restrict__ x,
    const float* __restrict__ Wl, const float* __restrict__ Wf,
    const float* __restrict__ bfilm,
    const float* __restrict__ Ws, const float* __restrict__ Wfs,
    __hip_bfloat16* __restrict__ hbuf, __hip_bfloat16* __restrict__ bgbuf,
    float* __restrict__ outbuf) {
    __shared__ float xs[16][128];
    __shared__ float sk[16][384]; // skip | beta_s | gamma_s
    const int t = threadIdx.x;
    const long node0 = (long)blockIdx.x * 16;

    { // stage x tile: 2048 floats = 512 float4
        const float4* src = (const float4*)(x + node0 * 128);
        float4* dst = (float4*)(&xs[0][0]);
        dst[t] = src[t];
        dst[t + 256] = src[t + 256];
    }
    __syncthreads();

    const int js[3] = { t, t + 256, t + 512 };
    const float* wp[3];
    int st[3];
    #pragma unroll
    for (int c = 0; c < 3; ++c) {
        int j = js[c];
        if (j < 128)      { wp[c] = Wl  + j;         st[c] = 128; }
        else if (j < 384) { wp[c] = Wf  + (j - 128); st[c] = 256; }
        else if (j < 512) { wp[c] = Ws  + (j - 384); st[c] = 128; }
        else              { wp[c] = Wfs + (j - 512); st[c] = 256; }
    }

    float acc[16][3];
    #pragma unroll
    for (int n = 0; n < 16; ++n)
        #pragma unroll
        for (int c = 0; c < 3; ++c) acc[n][c] = 0.f;

    const float* p0 = wp[0]; const float* p1 = wp[1]; const float* p2 = wp[2];
    const int s0 = st[0], s1 = st[1], s2 = st[2];
    for (int k0 = 0; k0 < 128; k0 += 4) {
        float w0[4], w1[4], w2[4];
        #pragma unroll
        for (int kk = 0; kk < 4; ++kk) {
            w0[kk] = p0[kk * s0];
            w1[kk] = p1[kk * s1];
            w2[kk] = p2[kk * s2];
        }
        p0 += 4 * s0; p1 += 4 * s1; p2 += 4 * s2;
        #pragma unroll
        for (int n = 0; n < 16; ++n) {
            float4 xv = *(const float4*)(&xs[n][k0]);
            acc[n][0] += xv.x * w0[0] + xv.y * w0[1] + xv.z * w0[2] + xv.w * w0[3];
            acc[n][1] += xv.x * w1[0] + xv.y * w1[1] + xv.z * w1[2] + xv.w * w1[3];
            acc[n][2] += xv.x * w2[0] + xv.y * w2[1] + xv.z * w2[2] + xv.w * w2[3];
        }
    }

    // epilogue: route per column group (wave-uniform branches; boundaries are x64)
    #pragma unroll
    for (int c = 0; c < 3; ++c) {
        int j = js[c];
        if (j < 128) {
            #pragma unroll
            for (int n = 0; n < 16; ++n)
                hbuf[(node0 + n) * 128 + j] = __float2bfloat16(acc[n][c]);
        } else if (j < 384) {
            float bb = bfilm[j - 128];
            #pragma unroll
            for (int n = 0; n < 16; ++n)
                bgbuf[(node0 + n) * 256 + (j - 128)] = __float2bfloat16(acc[n][c] + bb);
        } else {
            #pragma unroll
            for (int n = 0; n < 16; ++n)
                sk[n][j - 384] = acc[n][c];
        }
    }
    __syncthreads();

    for (int i = t; i < 16 * 128; i += 256) {
        int n = i >> 7, cc = i & 127;
        float sv = sk[n][cc];
        float bs = sk[n][128 + cc];
        float gs = sk[n][256 + cc];
        float o = fmaxf(gs * sv + bs, 0.f);
        outbuf[(node0 + n) * 128 + cc] = o;
    }
}

// ---------------------------------------------------------------------------
// Per-dst aggregation via CSR: agg = deg_inv * sum_src relu(gamma*h[src]+beta)
// x_next = maybe_relu(out + agg).  One block per node, 128 threads = 1 col each.
// ---------------------------------------------------------------------------
__global__ __launch_bounds__(128) void agg_kernel(
    const __hip_bfloat16* __restrict__ h, const __hip_bfloat16* __restrict__ bg,
    const int* __restrict__ row_ptr, const int* __restrict__ csr_src,
    const float* __restrict__ deg_inv, float* __restrict__ xn, int apply_relu) {
    const int v = blockIdx.x;
    const int c = threadIdx.x;
    const float beta  = __bfloat162float(bg[(size_t)v * 256 + c]);
    const float gamma = __bfloat162float(bg[(size_t)v * 256 + 128 + c]);
    const int b = row_ptr[v];
    const int e = row_ptr[v + 1];
    float acc = 0.f;
    for (int i = b; i < e; ++i) {
        int s = csr_src[i];
        float hv = __bfloat162float(h[(size_t)s * 128 + c]);
        acc += fmaxf(gamma * hv + beta, 0.f);
    }
    float o = xn[(size_t)v * 128 + c] + acc * deg_inv[v];
    if (apply_relu) o = fmaxf(o, 0.f);
    xn[(size_t)v * 128 + c] = o;
}

// ---------------------------------------------------------------------------
extern "C" void kernel_launch(void* const* d_in, const int* in_sizes, int n_in,
                              void* d_out, int out_size, void* d_ws, size_t ws_size,
                              hipStream_t stream) {
    const float*    x_in   = (const float*)d_in[0];
    const unsigned* eidx   = (const unsigned*)d_in[1];
    const float*    W_lin  = (const float*)d_in[2];
    const float*    W_film = (const float*)d_in[3];
    const float*    b_film = (const float*)d_in[4];
    const float*    W_skip = (const float*)d_in[5];
    const float*    W_fskip= (const float*)d_in[6];
    float*          out    = (float*)d_out;

    char* ws = (char*)d_ws;
    size_t off = 0;
    auto alloc = [&](size_t bytes) -> void* {
        void* p = ws + off;
        off = (off + bytes + 255) & ~(size_t)255;
        return p;
    };
    int*   flag      = (int*)alloc(4);
    int*   counts    = (int*)alloc((size_t)N_NODES * 4);
    int*   row_ptr   = (int*)alloc((size_t)(N_NODES + 1) * 4);
    int*   cursor    = (int*)alloc((size_t)N_NODES * 4);
    int*   blockSums = (int*)alloc(128 * 4);
    float* deg_inv   = (float*)alloc((size_t)N_NODES * 4);
    int*   csr_src   = (int*)alloc((size_t)N_EDGES * 4);
    __hip_bfloat16* hbuf  = (__hip_bfloat16*)alloc((size_t)N_NODES * 128 * 2);
    __hip_bfloat16* bgbuf = (__hip_bfloat16*)alloc((size_t)N_NODES * 256 * 2);
    float* xbufA = (float*)alloc((size_t)N_NODES * 128 * 4);
    (void)ws_size; (void)in_sizes; (void)n_in; (void)out_size;

    const int NB_SCAN = (N_NODES + 1023) / 1024; // 98
    const int EB = (N_EDGES + 255) / 256;        // 6250

    hipMemsetAsync(counts, 0, (size_t)N_NODES * 4, stream);
    detect_kernel<<<1, 256, 0, stream>>>(eidx, flag);
    hist_kernel<<<EB, 256, 0, stream>>>(eidx, flag, counts);
    scan1_kernel<<<NB_SCAN, 256, 0, stream>>>(counts, blockSums);
    scan2_kernel<<<1, 1, 0, stream>>>(blockSums, NB_SCAN, row_ptr);
    scan3_kernel<<<NB_SCAN, 256, 0, stream>>>(counts, blockSums, row_ptr, cursor, deg_inv);
    fill_kernel<<<EB, 256, 0, stream>>>(eidx, flag, cursor, csr_src);

    const float* xc = x_in;
    for (int l = 0; l < 4; ++l) {
        float* xn = (l & 1) ? out : xbufA;
        gemm_kernel<<<N_NODES / 16, 256, 0, stream>>>(
            xc,
            W_lin  + (size_t)l * 128 * 128,
            W_film + (size_t)l * 128 * 256,
            b_film + (size_t)l * 256,
            W_skip + (size_t)l * 128 * 128,
            W_fskip+ (size_t)l * 128 * 256,
            hbuf, bgbuf, xn);
        agg_kernel<<<N_NODES, 128, 0, stream>>>(
            hbuf, bgbuf, row_ptr, csr_src, deg_inv, xn, (l < 3) ? 1 : 0);
        xc = xn;
    }
}

// Round 2
// 1365.676 us; speedup vs baseline: 1.6921x; 1.6921x over previous
//
#include <hip/hip_runtime.h>
#include <hip/hip_bf16.h>

#define N_NODES 100000
#define N_PAD   100096   // padded to multiple of 128
#define N_EDGES 1600000

typedef __bf16 bf16x8 __attribute__((ext_vector_type(8)));
typedef float  f32x4  __attribute__((ext_vector_type(4)));

__device__ __forceinline__ void gload16(const void* g, void* s) {
    __builtin_amdgcn_global_load_lds(
        (const __attribute__((address_space(1))) unsigned int*)g,
        (__attribute__((address_space(3))) unsigned int*)s, 16, 0, 0);
}

// ---------------------------------------------------------------------------
// Edge-index width detection (int64 vs int32 layout in the buffer).
// ---------------------------------------------------------------------------
__global__ void detect_kernel(const unsigned* __restrict__ e, int* __restrict__ flag) {
    __shared__ int nz;
    if (threadIdx.x == 0) nz = 0;
    __syncthreads();
    int local = 0;
    for (int i = threadIdx.x; i < 1024; i += blockDim.x)
        if (e[2 * i + 1] != 0) local = 1;
    if (local) atomicOr(&nz, 1);
    __syncthreads();
    if (threadIdx.x == 0) *flag = (nz == 0) ? 1 : 0;
}

__device__ __forceinline__ int edge_at(const unsigned* __restrict__ e, long idx, int is64) {
    return (int)(is64 ? e[2 * idx] : e[idx]);
}

__global__ void hist_kernel(const unsigned* __restrict__ e, const int* __restrict__ flag,
                            int* __restrict__ counts) {
    int i = blockIdx.x * blockDim.x + threadIdx.x;
    if (i >= N_EDGES) return;
    int is64 = *flag;
    int d = edge_at(e, (long)N_EDGES + i, is64);
    atomicAdd(&counts[d], 1);
}

__global__ void scan1_kernel(const int* __restrict__ counts, int* __restrict__ blockSums) {
    __shared__ int red[256];
    int base = blockIdx.x * 1024;
    int sum = 0;
    for (int i = threadIdx.x; i < 1024; i += 256) {
        int idx = base + i;
        sum += (idx < N_NODES) ? counts[idx] : 0;
    }
    red[threadIdx.x] = sum;
    __syncthreads();
    for (int s = 128; s > 0; s >>= 1) {
        if (threadIdx.x < s) red[threadIdx.x] += red[threadIdx.x + s];
        __syncthreads();
    }
    if (threadIdx.x == 0) blockSums[blockIdx.x] = red[0];
}

__global__ void scan2_kernel(int* __restrict__ blockSums, int nb, int* __restrict__ row_ptr) {
    int run = 0;
    for (int i = 0; i < nb; ++i) { int v = blockSums[i]; blockSums[i] = run; run += v; }
    row_ptr[N_NODES] = run;
}

__global__ void scan3_kernel(const int* __restrict__ counts, const int* __restrict__ blockSums,
                             int* __restrict__ row_ptr, int* __restrict__ cursor,
                             float* __restrict__ deg_inv) {
    __shared__ int lds[256];
    int base = blockIdx.x * 1024;
    int t = threadIdx.x;
    int v[4];
    int s = 0;
    for (int i = 0; i < 4; ++i) {
        int idx = base + t * 4 + i;
        v[i] = (idx < N_NODES) ? counts[idx] : 0;
        s += v[i];
    }
    lds[t] = s;
    __syncthreads();
    for (int off = 1; off < 256; off <<= 1) {
        int add = (t >= off) ? lds[t - off] : 0;
        __syncthreads();
        lds[t] += add;
        __syncthreads();
    }
    int excl = lds[t] - s + blockSums[blockIdx.x];
    for (int i = 0; i < 4; ++i) {
        int idx = base + t * 4 + i;
        if (idx < N_NODES) {
            row_ptr[idx] = excl;
            cursor[idx]  = excl;
            deg_inv[idx] = 1.0f / fmaxf((float)v[i], 1.0f);
            excl += v[i];
        }
    }
}

__global__ void fill_kernel(const unsigned* __restrict__ e, const int* __restrict__ flag,
                            int* __restrict__ cursor, int* __restrict__ csr_src) {
    int i = blockIdx.x * blockDim.x + threadIdx.x;
    if (i >= N_EDGES) return;
    int is64 = *flag;
    int s = edge_at(e, (long)i, is64);
    int d = edge_at(e, (long)N_EDGES + i, is64);
    int pos = atomicAdd(&cursor[d], 1);
    csr_src[pos] = s;
}

// ---------------------------------------------------------------------------
// Weight prep: Bt[layer][n=768][k=384] bf16, column-major (n-major, k-contig).
// k in [0,128): W_hi ; [128,256): W_hi ; [256,384): W_lo.
// ---------------------------------------------------------------------------
__global__ void bt_prep_kernel(const float* __restrict__ Wl, const float* __restrict__ Wf,
                               const float* __restrict__ Ws, const float* __restrict__ Wfs,
                               __hip_bfloat16* __restrict__ Bt) {
    int idx = blockIdx.x * 256 + threadIdx.x;
    if (idx >= 4 * 768 * 384) return;
    int k   = idx % 384;
    int n   = (idx / 384) % 768;
    int lay = idx / (384 * 768);
    int kb = k >> 7, ks = k & 127;
    float w;
    if (n < 128)      w = Wl [(size_t)lay * 16384 + ks * 128 + n];
    else if (n < 384) w = Wf [(size_t)lay * 32768 + ks * 256 + (n - 128)];
    else if (n < 512) w = Ws [(size_t)lay * 16384 + ks * 128 + (n - 384)];
    else              w = Wfs[(size_t)lay * 32768 + ks * 256 + (n - 512)];
    __hip_bfloat16 hi = __float2bfloat16(w);
    Bt[idx] = (kb < 2) ? hi : __float2bfloat16(w - __bfloat162float(hi));
}

// x (f32) -> A planes: A[node][0:128]=hi, A[node][128:256]=lo
__global__ void xsplit_kernel(const float* __restrict__ x, __hip_bfloat16* __restrict__ A) {
    long i = (long)blockIdx.x * 256 + threadIdx.x;
    if (i >= (long)N_NODES * 128) return;
    long node = i >> 7; int c = (int)(i & 127);
    float v = x[i];
    __hip_bfloat16 hi = __float2bfloat16(v);
    A[node * 256 + c]       = hi;
    A[node * 256 + 128 + c] = __float2bfloat16(v - __bfloat162float(hi));
}

// ---------------------------------------------------------------------------
// MFMA GEMM: C[100000 x 768] = A[100000 x 384] @ B[384 x 768]
// A stored as [node][256] bf16 (hi|lo); logical k-blocks {hi,lo,hi}.
// Grid: 782 m-tiles x 6 n-tiles. Block 256 thr = 4 waves (2x2), 64x64/wave.
// Epilogue routes by n-tile: h(bf16) | beta,gamma(+b_film, bf16) | sk(f32) | bs,gs(bf16)
// ---------------------------------------------------------------------------
__global__ __launch_bounds__(256, 2) void mfma_gemm_kernel(
    const __hip_bfloat16* __restrict__ A,
    const __hip_bfloat16* __restrict__ Bt,   // this layer, [768][384]
    const float* __restrict__ bfilm,         // this layer, [256]
    __hip_bfloat16* __restrict__ hbuf,       // [N][128]
    __hip_bfloat16* __restrict__ bgbuf,      // [N][256]
    float* __restrict__ skp,                 // [N][128] f32 (= d_out)
    __hip_bfloat16* __restrict__ bsp,        // [N][128]
    __hip_bfloat16* __restrict__ gsp)        // [N][128]
{
    __shared__ alignas(16) unsigned char lds_raw[32768];
    unsigned char* ldsA = lds_raw;
    unsigned char* ldsB = lds_raw + 16384;

    const int t  = threadIdx.x;
    const int mt = blockIdx.x / 6;
    const int jt = blockIdx.x % 6;
    const long node0 = (long)mt * 128;
    const int w  = t >> 6, l = t & 63;
    const int wm = w >> 1, wn = w & 1;
    const int lr = l & 15;            // fragment row/col index
    const int kq16 = (l >> 4) << 4;   // k-quarter byte offset
    const int sw = (lr & 7) << 4;     // read-side XOR swizzle

    const int sr  = t >> 3;           // staging row within 32-row group
    const int scb = (t & 7) << 4;     // staging col-byte
    const int scbs = scb ^ ((sr & 7) << 4); // source-side inverse swizzle

    const char* Abase = (const char*)A;
    const char* Bbase = (const char*)Bt + (size_t)(jt * 128) * 768; // row stride 384*2=768B

    f32x4 acc[4][4];
    #pragma unroll
    for (int mi = 0; mi < 4; ++mi)
        #pragma unroll
        for (int ni = 0; ni < 4; ++ni)
            #pragma unroll
            for (int j = 0; j < 4; ++j) acc[mi][ni][j] = 0.f;

    for (int ks = 0; ks < 6; ++ks) {
        const int k0 = ks * 64;
        const int kcolA = (k0 < 256) ? k0 : (k0 - 256);
        // stage A-tile [128][64] and B-tile [128 n][64 k] (both 16KB)
        #pragma unroll
        for (int i = 0; i < 4; ++i) {
            const int r = (i << 5) + sr;
            gload16(Abase + (node0 + r) * 512 + (size_t)kcolA * 2 + scbs,
                    ldsA + (((i << 8) + t) << 4));
            gload16(Bbase + (size_t)r * 768 + (size_t)k0 * 2 + scbs,
                    ldsB + (((i << 8) + t) << 4));
        }
        __syncthreads();   // drains vmcnt before any wave reads LDS

        #pragma unroll
        for (int kh = 0; kh < 2; ++kh) {
            const int kbs = ((kh << 6) + kq16) ^ sw;
            bf16x8 af[4], bfr[4];
            #pragma unroll
            for (int mi = 0; mi < 4; ++mi)
                af[mi] = *(const bf16x8*)(ldsA + (wm * 64 + mi * 16 + lr) * 128 + kbs);
            #pragma unroll
            for (int ni = 0; ni < 4; ++ni)
                bfr[ni] = *(const bf16x8*)(ldsB + (wn * 64 + ni * 16 + lr) * 128 + kbs);
            #pragma unroll
            for (int mi = 0; mi < 4; ++mi)
                #pragma unroll
                for (int ni = 0; ni < 4; ++ni)
                    acc[mi][ni] = __builtin_amdgcn_mfma_f32_16x16x32_bf16(
                        af[mi], bfr[ni], acc[mi][ni], 0, 0, 0);
        }
        __syncthreads();   // protect LDS before next stage
    }

    // epilogue: C/D layout col=lane&15, row=(lane>>4)*4+j   [m89/m91-verified]
    const int col = lr;
    const int rb  = (l >> 4) << 2;
    if (jt == 0) {
        #pragma unroll
        for (int mi = 0; mi < 4; ++mi)
            #pragma unroll
            for (int ni = 0; ni < 4; ++ni) {
                const int n = wn * 64 + ni * 16 + col;
                #pragma unroll
                for (int j = 0; j < 4; ++j) {
                    long node = node0 + wm * 64 + mi * 16 + rb + j;
                    if (node < N_NODES)
                        hbuf[node * 128 + n] = __float2bfloat16(acc[mi][ni][j]);
                }
            }
    } else if (jt <= 2) {
        const int c0 = (jt - 1) * 128;
        #pragma unroll
        for (int mi = 0; mi < 4; ++mi)
            #pragma unroll
            for (int ni = 0; ni < 4; ++ni) {
                const int n = wn * 64 + ni * 16 + col;
                const float bb = bfilm[c0 + n];
                #pragma unroll
                for (int j = 0; j < 4; ++j) {
                    long node = node0 + wm * 64 + mi * 16 + rb + j;
                    if (node < N_NODES)
                        bgbuf[node * 256 + c0 + n] = __float2bfloat16(acc[mi][ni][j] + bb);
                }
            }
    } else if (jt == 3) {
        #pragma unroll
        for (int mi = 0; mi < 4; ++mi)
            #pragma unroll
            for (int ni = 0; ni < 4; ++ni) {
                const int n = wn * 64 + ni * 16 + col;
                #pragma unroll
                for (int j = 0; j < 4; ++j) {
                    long node = node0 + wm * 64 + mi * 16 + rb + j;
                    if (node < N_NODES)
                        skp[node * 128 + n] = acc[mi][ni][j];
                }
            }
    } else {
        __hip_bfloat16* dst = (jt == 4) ? bsp : gsp;
        #pragma unroll
        for (int mi = 0; mi < 4; ++mi)
            #pragma unroll
            for (int ni = 0; ni < 4; ++ni) {
                const int n = wn * 64 + ni * 16 + col;
                #pragma unroll
                for (int j = 0; j < 4; ++j) {
                    long node = node0 + wm * 64 + mi * 16 + rb + j;
                    if (node < N_NODES)
                        dst[node * 128 + n] = __float2bfloat16(acc[mi][ni][j]);
                }
            }
    }
}

// ---------------------------------------------------------------------------
// Aggregation + fused skip epilogue + next-layer split write.
// out = relu(gs*sk + bs);  o = out + deg_inv * sum relu(gamma*h[s]+beta)
// l<3: o=relu(o) -> write (hi,lo) bf16 planes of A ; l==3: write f32 d_out.
// ---------------------------------------------------------------------------
__global__ __launch_bounds__(128) void agg_kernel(
    const __hip_bfloat16* __restrict__ h, const __hip_bfloat16* __restrict__ bg,
    const int* __restrict__ row_ptr, const int* __restrict__ csr_src,
    const float* __restrict__ deg_inv,
    const float* __restrict__ skp, const __hip_bfloat16* __restrict__ bsp,
    const __hip_bfloat16* __restrict__ gsp,
    __hip_bfloat16* __restrict__ Anext, float* __restrict__ fout, int apply_relu)
{
    const int v = blockIdx.x;
    const int c = threadIdx.x;
    const float beta  = __bfloat162float(bg[(size_t)v * 256 + c]);
    const float gamma = __bfloat162float(bg[(size_t)v * 256 + 128 + c]);
    const int b = row_ptr[v];
    const int e = row_ptr[v + 1];
    float acc = 0.f;
    for (int i = b; i < e; ++i) {
        int s = csr_src[i];
        float hv = __bfloat162float(h[(size_t)s * 128 + c]);
        acc += fmaxf(gamma * hv + beta, 0.f);
    }
    const float sk = skp[(size_t)v * 128 + c];
    const float bs = __bfloat162float(bsp[(size_t)v * 128 + c]);
    const float gs = __bfloat162float(gsp[(size_t)v * 128 + c]);
    float o = fmaxf(gs * sk + bs, 0.f) + acc * deg_inv[v];
    if (apply_relu) o = fmaxf(o, 0.f);
    if (Anext) {
        __hip_bfloat16 hi = __float2bfloat16(o);
        Anext[(size_t)v * 256 + c]       = hi;
        Anext[(size_t)v * 256 + 128 + c] = __float2bfloat16(o - __bfloat162float(hi));
    } else {
        fout[(size_t)v * 128 + c] = o;
    }
}

// ---------------------------------------------------------------------------
extern "C" void kernel_launch(void* const* d_in, const int* in_sizes, int n_in,
                              void* d_out, int out_size, void* d_ws, size_t ws_size,
                              hipStream_t stream) {
    const float*    x_in    = (const float*)d_in[0];
    const unsigned* eidx    = (const unsigned*)d_in[1];
    const float*    W_lin   = (const float*)d_in[2];
    const float*    W_film  = (const float*)d_in[3];
    const float*    b_film  = (const float*)d_in[4];
    const float*    W_skip  = (const float*)d_in[5];
    const float*    W_fskip = (const float*)d_in[6];
    float*          out     = (float*)d_out;

    char* ws = (char*)d_ws;
    size_t off = 0;
    auto alloc = [&](size_t bytes) -> void* {
        void* p = ws + off;
        off = (off + bytes + 255) & ~(size_t)255;
        return p;
    };
    int*   flag      = (int*)alloc(4);
    int*   counts    = (int*)alloc((size_t)N_NODES * 4);
    int*   row_ptr   = (int*)alloc((size_t)(N_NODES + 1) * 4);
    int*   cursor    = (int*)alloc((size_t)N_NODES * 4);
    int*   blockSums = (int*)alloc(128 * 4);
    float* deg_inv   = (float*)alloc((size_t)N_NODES * 4);
    int*   csr_src   = (int*)alloc((size_t)N_EDGES * 4);
    __hip_bfloat16* Abuf  = (__hip_bfloat16*)alloc((size_t)N_PAD * 256 * 2);
    __hip_bfloat16* BtAll = (__hip_bfloat16*)alloc((size_t)4 * 768 * 384 * 2);
    __hip_bfloat16* hbuf  = (__hip_bfloat16*)alloc((size_t)N_NODES * 128 * 2);
    __hip_bfloat16* bgbuf = (__hip_bfloat16*)alloc((size_t)N_NODES * 256 * 2);
    __hip_bfloat16* bsp   = (__hip_bfloat16*)alloc((size_t)N_NODES * 128 * 2);
    __hip_bfloat16* gsp   = (__hip_bfloat16*)alloc((size_t)N_NODES * 128 * 2);
    float* skp = out;  // d_out doubles as the f32 skip plane
    (void)ws_size; (void)in_sizes; (void)n_in; (void)out_size;

    const int NB_SCAN = (N_NODES + 1023) / 1024; // 98
    const int EB = (N_EDGES + 255) / 256;        // 6250

    hipMemsetAsync(counts, 0, (size_t)N_NODES * 4, stream);
    detect_kernel<<<1, 256, 0, stream>>>(eidx, flag);
    hist_kernel<<<EB, 256, 0, stream>>>(eidx, flag, counts);
    scan1_kernel<<<NB_SCAN, 256, 0, stream>>>(counts, blockSums);
    scan2_kernel<<<1, 1, 0, stream>>>(blockSums, NB_SCAN, row_ptr);
    scan3_kernel<<<NB_SCAN, 256, 0, stream>>>(counts, blockSums, row_ptr, cursor, deg_inv);
    fill_kernel<<<EB, 256, 0, stream>>>(eidx, flag, cursor, csr_src);

    xsplit_kernel<<<(N_NODES * 128 + 255) / 256, 256, 0, stream>>>(x_in, Abuf);
    bt_prep_kernel<<<(4 * 768 * 384 + 255) / 256, 256, 0, stream>>>(
        W_lin, W_film, W_skip, W_fskip, BtAll);

    const int MT = N_PAD / 128; // 782
    for (int l = 0; l < 4; ++l) {
        mfma_gemm_kernel<<<MT * 6, 256, 0, stream>>>(
            Abuf,
            BtAll + (size_t)l * 768 * 384,
            b_film + (size_t)l * 256,
            hbuf, bgbuf, skp, bsp, gsp);
        agg_kernel<<<N_NODES, 128, 0, stream>>>(
            hbuf, bgbuf, row_ptr, csr_src, deg_inv,
            skp, bsp, gsp,
            (l < 3) ? Abuf : (__hip_bfloat16*)nullptr,
            (l == 3) ? out : (float*)nullptr,
            (l < 3) ? 1 : 0);
    }
}

// Round 3
// 996.165 us; speedup vs baseline: 2.3198x; 1.3709x over previous
//
#include <hip/hip_runtime.h>
#include <hip/hip_bf16.h>

#define N_NODES 100000
#define N_PAD   100096   // padded to multiple of 128
#define N_EDGES 1600000

typedef __bf16 bf16x8 __attribute__((ext_vector_type(8)));
typedef float  f32x4  __attribute__((ext_vector_type(4)));

__device__ __forceinline__ void gload16(const void* g, void* s) {
    __builtin_amdgcn_global_load_lds(
        (const __attribute__((address_space(1))) unsigned int*)g,
        (__attribute__((address_space(3))) unsigned int*)s, 16, 0, 0);
}

// unpack a uint holding two bf16 (lo = element 2l, hi = element 2l+1)
__device__ __forceinline__ float2 bf2f(unsigned p) {
    float2 r;
    union { unsigned u; float f; } a, b;
    a.u = p << 16;
    b.u = p & 0xffff0000u;
    r.x = a.f; r.y = b.f;
    return r;
}
__device__ __forceinline__ unsigned f2bf2(float x, float y) {
    unsigned lo = (unsigned)__builtin_bit_cast(unsigned short, __float2bfloat16(x));
    unsigned hi = (unsigned)__builtin_bit_cast(unsigned short, __float2bfloat16(y));
    return lo | (hi << 16);
}

// ---------------------------------------------------------------------------
// Edge-index width detection (int64 vs int32 layout in the buffer).
// ---------------------------------------------------------------------------
__global__ void detect_kernel(const unsigned* __restrict__ e, int* __restrict__ flag) {
    __shared__ int nz;
    if (threadIdx.x == 0) nz = 0;
    __syncthreads();
    int local = 0;
    for (int i = threadIdx.x; i < 1024; i += blockDim.x)
        if (e[2 * i + 1] != 0) local = 1;
    if (local) atomicOr(&nz, 1);
    __syncthreads();
    if (threadIdx.x == 0) *flag = (nz == 0) ? 1 : 0;
}

__device__ __forceinline__ int edge_at(const unsigned* __restrict__ e, long idx, int is64) {
    return (int)(is64 ? e[2 * idx] : e[idx]);
}

__global__ void hist_kernel(const unsigned* __restrict__ e, const int* __restrict__ flag,
                            int* __restrict__ counts) {
    int i = blockIdx.x * blockDim.x + threadIdx.x;
    if (i >= N_EDGES) return;
    int is64 = *flag;
    int d = edge_at(e, (long)N_EDGES + i, is64);
    atomicAdd(&counts[d], 1);
}

__global__ void scan1_kernel(const int* __restrict__ counts, int* __restrict__ blockSums) {
    __shared__ int red[256];
    int base = blockIdx.x * 1024;
    int sum = 0;
    for (int i = threadIdx.x; i < 1024; i += 256) {
        int idx = base + i;
        sum += (idx < N_NODES) ? counts[idx] : 0;
    }
    red[threadIdx.x] = sum;
    __syncthreads();
    for (int s = 128; s > 0; s >>= 1) {
        if (threadIdx.x < s) red[threadIdx.x] += red[threadIdx.x + s];
        __syncthreads();
    }
    if (threadIdx.x == 0) blockSums[blockIdx.x] = red[0];
}

__global__ void scan2_kernel(int* __restrict__ blockSums, int nb, int* __restrict__ row_ptr) {
    int run = 0;
    for (int i = 0; i < nb; ++i) { int v = blockSums[i]; blockSums[i] = run; run += v; }
    row_ptr[N_NODES] = run;
}

__global__ void scan3_kernel(const int* __restrict__ counts, const int* __restrict__ blockSums,
                             int* __restrict__ row_ptr, int* __restrict__ cursor,
                             float* __restrict__ deg_inv) {
    __shared__ int lds[256];
    int base = blockIdx.x * 1024;
    int t = threadIdx.x;
    int v[4];
    int s = 0;
    for (int i = 0; i < 4; ++i) {
        int idx = base + t * 4 + i;
        v[i] = (idx < N_NODES) ? counts[idx] : 0;
        s += v[i];
    }
    lds[t] = s;
    __syncthreads();
    for (int off = 1; off < 256; off <<= 1) {
        int add = (t >= off) ? lds[t - off] : 0;
        __syncthreads();
        lds[t] += add;
        __syncthreads();
    }
    int excl = lds[t] - s + blockSums[blockIdx.x];
    for (int i = 0; i < 4; ++i) {
        int idx = base + t * 4 + i;
        if (idx < N_NODES) {
            row_ptr[idx] = excl;
            cursor[idx]  = excl;
            deg_inv[idx] = 1.0f / fmaxf((float)v[i], 1.0f);
            excl += v[i];
        }
    }
}

__global__ void fill_kernel(const unsigned* __restrict__ e, const int* __restrict__ flag,
                            int* __restrict__ cursor, int* __restrict__ csr_src) {
    int i = blockIdx.x * blockDim.x + threadIdx.x;
    if (i >= N_EDGES) return;
    int is64 = *flag;
    int s = edge_at(e, (long)i, is64);
    int d = edge_at(e, (long)N_EDGES + i, is64);
    int pos = atomicAdd(&cursor[d], 1);
    csr_src[pos] = s;
}

// ---------------------------------------------------------------------------
// Weight prep: Bt[layer][n=768][k=384] bf16, column-major (n-major, k-contig).
// ---------------------------------------------------------------------------
__global__ void bt_prep_kernel(const float* __restrict__ Wl, const float* __restrict__ Wf,
                               const float* __restrict__ Ws, const float* __restrict__ Wfs,
                               __hip_bfloat16* __restrict__ Bt) {
    int idx = blockIdx.x * 256 + threadIdx.x;
    if (idx >= 4 * 768 * 384) return;
    int k   = idx % 384;
    int n   = (idx / 384) % 768;
    int lay = idx / (384 * 768);
    int kb = k >> 7, ks = k & 127;
    float w;
    if (n < 128)      w = Wl [(size_t)lay * 16384 + ks * 128 + n];
    else if (n < 384) w = Wf [(size_t)lay * 32768 + ks * 256 + (n - 128)];
    else if (n < 512) w = Ws [(size_t)lay * 16384 + ks * 128 + (n - 384)];
    else              w = Wfs[(size_t)lay * 32768 + ks * 256 + (n - 512)];
    __hip_bfloat16 hi = __float2bfloat16(w);
    Bt[idx] = (kb < 2) ? hi : __float2bfloat16(w - __bfloat162float(hi));
}

// x (f32) -> A planes: A[node][0:128]=hi, A[node][128:256]=lo
__global__ void xsplit_kernel(const float* __restrict__ x, __hip_bfloat16* __restrict__ A) {
    long i = (long)blockIdx.x * 256 + threadIdx.x;
    if (i >= (long)N_NODES * 128) return;
    long node = i >> 7; int c = (int)(i & 127);
    float v = x[i];
    __hip_bfloat16 hi = __float2bfloat16(v);
    A[node * 256 + c]       = hi;
    A[node * 256 + 128 + c] = __float2bfloat16(v - __bfloat162float(hi));
}

// ---------------------------------------------------------------------------
// MFMA GEMM: C[100000 x 768] = A[100000 x 384] @ B[384 x 768]  (unchanged)
// ---------------------------------------------------------------------------
__global__ __launch_bounds__(256, 2) void mfma_gemm_kernel(
    const __hip_bfloat16* __restrict__ A,
    const __hip_bfloat16* __restrict__ Bt,
    const float* __restrict__ bfilm,
    __hip_bfloat16* __restrict__ hbuf,
    __hip_bfloat16* __restrict__ bgbuf,
    float* __restrict__ skp,
    __hip_bfloat16* __restrict__ bsp,
    __hip_bfloat16* __restrict__ gsp)
{
    __shared__ alignas(16) unsigned char lds_raw[32768];
    unsigned char* ldsA = lds_raw;
    unsigned char* ldsB = lds_raw + 16384;

    const int t  = threadIdx.x;
    const int mt = blockIdx.x / 6;
    const int jt = blockIdx.x % 6;
    const long node0 = (long)mt * 128;
    const int w  = t >> 6, l = t & 63;
    const int wm = w >> 1, wn = w & 1;
    const int lr = l & 15;
    const int kq16 = (l >> 4) << 4;
    const int sw = (lr & 7) << 4;

    const int sr  = t >> 3;
    const int scb = (t & 7) << 4;
    const int scbs = scb ^ ((sr & 7) << 4);

    const char* Abase = (const char*)A;
    const char* Bbase = (const char*)Bt + (size_t)(jt * 128) * 768;

    f32x4 acc[4][4];
    #pragma unroll
    for (int mi = 0; mi < 4; ++mi)
        #pragma unroll
        for (int ni = 0; ni < 4; ++ni)
            #pragma unroll
            for (int j = 0; j < 4; ++j) acc[mi][ni][j] = 0.f;

    for (int ks = 0; ks < 6; ++ks) {
        const int k0 = ks * 64;
        const int kcolA = (k0 < 256) ? k0 : (k0 - 256);
        #pragma unroll
        for (int i = 0; i < 4; ++i) {
            const int r = (i << 5) + sr;
            gload16(Abase + (node0 + r) * 512 + (size_t)kcolA * 2 + scbs,
                    ldsA + (((i << 8) + t) << 4));
            gload16(Bbase + (size_t)r * 768 + (size_t)k0 * 2 + scbs,
                    ldsB + (((i << 8) + t) << 4));
        }
        __syncthreads();

        #pragma unroll
        for (int kh = 0; kh < 2; ++kh) {
            const int kbs = ((kh << 6) + kq16) ^ sw;
            bf16x8 af[4], bfr[4];
            #pragma unroll
            for (int mi = 0; mi < 4; ++mi)
                af[mi] = *(const bf16x8*)(ldsA + (wm * 64 + mi * 16 + lr) * 128 + kbs);
            #pragma unroll
            for (int ni = 0; ni < 4; ++ni)
                bfr[ni] = *(const bf16x8*)(ldsB + (wn * 64 + ni * 16 + lr) * 128 + kbs);
            #pragma unroll
            for (int mi = 0; mi < 4; ++mi)
                #pragma unroll
                for (int ni = 0; ni < 4; ++ni)
                    acc[mi][ni] = __builtin_amdgcn_mfma_f32_16x16x32_bf16(
                        af[mi], bfr[ni], acc[mi][ni], 0, 0, 0);
        }
        __syncthreads();
    }

    const int col = lr;
    const int rb  = (l >> 4) << 2;
    if (jt == 0) {
        #pragma unroll
        for (int mi = 0; mi < 4; ++mi)
            #pragma unroll
            for (int ni = 0; ni < 4; ++ni) {
                const int n = wn * 64 + ni * 16 + col;
                #pragma unroll
                for (int j = 0; j < 4; ++j) {
                    long node = node0 + wm * 64 + mi * 16 + rb + j;
                    if (node < N_NODES)
                        hbuf[node * 128 + n] = __float2bfloat16(acc[mi][ni][j]);
                }
            }
    } else if (jt <= 2) {
        const int c0 = (jt - 1) * 128;
        #pragma unroll
        for (int mi = 0; mi < 4; ++mi)
            #pragma unroll
            for (int ni = 0; ni < 4; ++ni) {
                const int n = wn * 64 + ni * 16 + col;
                const float bb = bfilm[c0 + n];
                #pragma unroll
                for (int j = 0; j < 4; ++j) {
                    long node = node0 + wm * 64 + mi * 16 + rb + j;
                    if (node < N_NODES)
                        bgbuf[node * 256 + c0 + n] = __float2bfloat16(acc[mi][ni][j] + bb);
                }
            }
    } else if (jt == 3) {
        #pragma unroll
        for (int mi = 0; mi < 4; ++mi)
            #pragma unroll
            for (int ni = 0; ni < 4; ++ni) {
                const int n = wn * 64 + ni * 16 + col;
                #pragma unroll
                for (int j = 0; j < 4; ++j) {
                    long node = node0 + wm * 64 + mi * 16 + rb + j;
                    if (node < N_NODES)
                        skp[node * 128 + n] = acc[mi][ni][j];
                }
            }
    } else {
        __hip_bfloat16* dst = (jt == 4) ? bsp : gsp;
        #pragma unroll
        for (int mi = 0; mi < 4; ++mi)
            #pragma unroll
            for (int ni = 0; ni < 4; ++ni) {
                const int n = wn * 64 + ni * 16 + col;
                #pragma unroll
                for (int j = 0; j < 4; ++j) {
                    long node = node0 + wm * 64 + mi * 16 + rb + j;
                    if (node < N_NODES)
                        dst[node * 128 + n] = __float2bfloat16(acc[mi][ni][j]);
                }
            }
    }
}

// ---------------------------------------------------------------------------
// Aggregation v2: 1 wave per node, lane owns cols {2l, 2l+1} (uint = 2 bf16).
// Edge loop unrolled x4 with 4 independent accumulators -> 4 gathers in flight.
// ---------------------------------------------------------------------------
__global__ __launch_bounds__(256) void agg_kernel(
    const unsigned* __restrict__ h2,      // hbuf  [N][64] uint
    const unsigned* __restrict__ bg2,     // bgbuf [N][128] uint (beta 0..63 | gamma 64..127)
    const int* __restrict__ row_ptr, const int* __restrict__ csr_src,
    const float* __restrict__ deg_inv,
    const float* __restrict__ skp,        // [N][128] f32
    const unsigned* __restrict__ bsp2,    // [N][64] uint
    const unsigned* __restrict__ gsp2,    // [N][64] uint
    unsigned* __restrict__ Anext2,        // [N][128] uint (hi 0..63 | lo 64..127)
    float* __restrict__ fout, int apply_relu)
{
    const int t = threadIdx.x;
    const int v = blockIdx.x * 4 + (t >> 6);
    const int l = t & 63;

    const float2 beta  = bf2f(bg2[(size_t)v * 128 + l]);
    const float2 gamma = bf2f(bg2[(size_t)v * 128 + 64 + l]);
    const float2 sk = *(const float2*)(skp + (size_t)v * 128 + 2 * l);
    const float2 bs = bf2f(bsp2[(size_t)v * 64 + l]);
    const float2 gs = bf2f(gsp2[(size_t)v * 64 + l]);
    const float dinv = deg_inv[v];

    const int b = row_ptr[v];
    const int e = row_ptr[v + 1];

    float2 a0 = {0.f, 0.f}, a1 = {0.f, 0.f}, a2 = {0.f, 0.f}, a3 = {0.f, 0.f};
    int i = b;
    for (; i + 4 <= e; i += 4) {
        const int s0 = csr_src[i];
        const int s1 = csr_src[i + 1];
        const int s2 = csr_src[i + 2];
        const int s3 = csr_src[i + 3];
        const unsigned p0 = h2[(size_t)s0 * 64 + l];
        const unsigned p1 = h2[(size_t)s1 * 64 + l];
        const unsigned p2 = h2[(size_t)s2 * 64 + l];
        const unsigned p3 = h2[(size_t)s3 * 64 + l];
        float2 h0 = bf2f(p0), h1 = bf2f(p1), h2f = bf2f(p2), h3 = bf2f(p3);
        a0.x += fmaxf(gamma.x * h0.x + beta.x, 0.f);
        a0.y += fmaxf(gamma.y * h0.y + beta.y, 0.f);
        a1.x += fmaxf(gamma.x * h1.x + beta.x, 0.f);
        a1.y += fmaxf(gamma.y * h1.y + beta.y, 0.f);
        a2.x += fmaxf(gamma.x * h2f.x + beta.x, 0.f);
        a2.y += fmaxf(gamma.y * h2f.y + beta.y, 0.f);
        a3.x += fmaxf(gamma.x * h3.x + beta.x, 0.f);
        a3.y += fmaxf(gamma.y * h3.y + beta.y, 0.f);
    }
    for (; i < e; ++i) {
        const int s0 = csr_src[i];
        float2 h0 = bf2f(h2[(size_t)s0 * 64 + l]);
        a0.x += fmaxf(gamma.x * h0.x + beta.x, 0.f);
        a0.y += fmaxf(gamma.y * h0.y + beta.y, 0.f);
    }
    float2 acc;
    acc.x = (a0.x + a1.x) + (a2.x + a3.x);
    acc.y = (a0.y + a1.y) + (a2.y + a3.y);

    float o0 = fmaxf(gs.x * sk.x + bs.x, 0.f) + acc.x * dinv;
    float o1 = fmaxf(gs.y * sk.y + bs.y, 0.f) + acc.y * dinv;
    if (apply_relu) { o0 = fmaxf(o0, 0.f); o1 = fmaxf(o1, 0.f); }

    if (Anext2) {
        // hi plane at [v][c], lo plane at [v][128+c]
        unsigned hi = f2bf2(o0, o1);
        float r0, r1;
        { union { unsigned u; float f; } a; a.u = hi << 16;        r0 = o0 - a.f; }
        { union { unsigned u; float f; } a; a.u = hi & 0xffff0000u; r1 = o1 - a.f; }
        Anext2[(size_t)v * 128 + l]      = hi;
        Anext2[(size_t)v * 128 + 64 + l] = f2bf2(r0, r1);
    } else {
        *(float2*)(fout + (size_t)v * 128 + 2 * l) = make_float2(o0, o1);
    }
}

// ---------------------------------------------------------------------------
extern "C" void kernel_launch(void* const* d_in, const int* in_sizes, int n_in,
                              void* d_out, int out_size, void* d_ws, size_t ws_size,
                              hipStream_t stream) {
    const float*    x_in    = (const float*)d_in[0];
    const unsigned* eidx    = (const unsigned*)d_in[1];
    const float*    W_lin   = (const float*)d_in[2];
    const float*    W_film  = (const float*)d_in[3];
    const float*    b_film  = (const float*)d_in[4];
    const float*    W_skip  = (const float*)d_in[5];
    const float*    W_fskip = (const float*)d_in[6];
    float*          out     = (float*)d_out;

    char* ws = (char*)d_ws;
    size_t off = 0;
    auto alloc = [&](size_t bytes) -> void* {
        void* p = ws + off;
        off = (off + bytes + 255) & ~(size_t)255;
        return p;
    };
    int*   flag      = (int*)alloc(4);
    int*   counts    = (int*)alloc((size_t)N_NODES * 4);
    int*   row_ptr   = (int*)alloc((size_t)(N_NODES + 1) * 4);
    int*   cursor    = (int*)alloc((size_t)N_NODES * 4);
    int*   blockSums = (int*)alloc(128 * 4);
    float* deg_inv   = (float*)alloc((size_t)N_NODES * 4);
    int*   csr_src   = (int*)alloc((size_t)N_EDGES * 4);
    __hip_bfloat16* Abuf  = (__hip_bfloat16*)alloc((size_t)N_PAD * 256 * 2);
    __hip_bfloat16* BtAll = (__hip_bfloat16*)alloc((size_t)4 * 768 * 384 * 2);
    __hip_bfloat16* hbuf  = (__hip_bfloat16*)alloc((size_t)N_NODES * 128 * 2);
    __hip_bfloat16* bgbuf = (__hip_bfloat16*)alloc((size_t)N_NODES * 256 * 2);
    __hip_bfloat16* bsp   = (__hip_bfloat16*)alloc((size_t)N_NODES * 128 * 2);
    __hip_bfloat16* gsp   = (__hip_bfloat16*)alloc((size_t)N_NODES * 128 * 2);
    float* skp = out;
    (void)ws_size; (void)in_sizes; (void)n_in; (void)out_size;

    const int NB_SCAN = (N_NODES + 1023) / 1024; // 98
    const int EB = (N_EDGES + 255) / 256;        // 6250

    hipMemsetAsync(counts, 0, (size_t)N_NODES * 4, stream);
    detect_kernel<<<1, 256, 0, stream>>>(eidx, flag);
    hist_kernel<<<EB, 256, 0, stream>>>(eidx, flag, counts);
    scan1_kernel<<<NB_SCAN, 256, 0, stream>>>(counts, blockSums);
    scan2_kernel<<<1, 1, 0, stream>>>(blockSums, NB_SCAN, row_ptr);
    scan3_kernel<<<NB_SCAN, 256, 0, stream>>>(counts, blockSums, row_ptr, cursor, deg_inv);
    fill_kernel<<<EB, 256, 0, stream>>>(eidx, flag, cursor, csr_src);

    xsplit_kernel<<<(N_NODES * 128 + 255) / 256, 256, 0, stream>>>(x_in, Abuf);
    bt_prep_kernel<<<(4 * 768 * 384 + 255) / 256, 256, 0, stream>>>(
        W_lin, W_film, W_skip, W_fskip, BtAll);

    const int MT = N_PAD / 128; // 782
    const int AGG_B = (N_NODES + 3) / 4; // 25000
    for (int l = 0; l < 4; ++l) {
        mfma_gemm_kernel<<<MT * 6, 256, 0, stream>>>(
            Abuf,
            BtAll + (size_t)l * 768 * 384,
            b_film + (size_t)l * 256,
            hbuf, bgbuf, skp, bsp, gsp);
        agg_kernel<<<AGG_B, 256, 0, stream>>>(
            (const unsigned*)hbuf, (const unsigned*)bgbuf,
            row_ptr, csr_src, deg_inv,
            skp, (const unsigned*)bsp, (const unsigned*)gsp,
            (l < 3) ? (unsigned*)Abuf : (unsigned*)nullptr,
            (l == 3) ? out : (float*)nullptr,
            (l < 3) ? 1 : 0);
    }
}

// Round 4
// 848.521 us; speedup vs baseline: 2.7234x; 1.1740x over previous
//
#include <hip/hip_runtime.h>
#include <hip/hip_bf16.h>

#define N_NODES 100000
#define N_PAD   100096   // padded to multiple of 128
#define N_EDGES 1600000
#define NXCD    8
#define NRANGE  ((N_NODES + NXCD - 1) / NXCD)   // 12500
#define NSLICE  256

typedef __bf16 bf16x8 __attribute__((ext_vector_type(8)));
typedef float  f32x4  __attribute__((ext_vector_type(4)));

__device__ __forceinline__ void gload16(const void* g, void* s) {
    __builtin_amdgcn_global_load_lds(
        (const __attribute__((address_space(1))) unsigned int*)g,
        (__attribute__((address_space(3))) unsigned int*)s, 16, 0, 0);
}

// unpack a uint holding two bf16 (lo = element 2l, hi = element 2l+1)
__device__ __forceinline__ float2 bf2f(unsigned p) {
    float2 r;
    union { unsigned u; float f; } a, b;
    a.u = p << 16;
    b.u = p & 0xffff0000u;
    r.x = a.f; r.y = b.f;
    return r;
}
__device__ __forceinline__ unsigned f2bf2(float x, float y) {
    unsigned lo = (unsigned)__builtin_bit_cast(unsigned short, __float2bfloat16(x));
    unsigned hi = (unsigned)__builtin_bit_cast(unsigned short, __float2bfloat16(y));
    return lo | (hi << 16);
}

// ---------------------------------------------------------------------------
// Edge-index width detection (int64 vs int32 layout in the buffer).
// ---------------------------------------------------------------------------
__global__ void detect_kernel(const unsigned* __restrict__ e, int* __restrict__ flag) {
    __shared__ int nz;
    if (threadIdx.x == 0) nz = 0;
    __syncthreads();
    int local = 0;
    for (int i = threadIdx.x; i < 1024; i += blockDim.x)
        if (e[2 * i + 1] != 0) local = 1;
    if (local) atomicOr(&nz, 1);
    __syncthreads();
    if (threadIdx.x == 0) *flag = (nz == 0) ? 1 : 0;
}

__device__ __forceinline__ int edge_at(const unsigned* __restrict__ e, long idx, int is64) {
    return (int)(is64 ? e[2 * idx] : e[idx]);
}

__global__ void hist_kernel(const unsigned* __restrict__ e, const int* __restrict__ flag,
                            int* __restrict__ counts) {
    int i = blockIdx.x * blockDim.x + threadIdx.x;
    if (i >= N_EDGES) return;
    int is64 = *flag;
    int d = edge_at(e, (long)N_EDGES + i, is64);
    atomicAdd(&counts[d], 1);
}

__global__ void scan1_kernel(const int* __restrict__ counts, int* __restrict__ blockSums) {
    __shared__ int red[256];
    int base = blockIdx.x * 1024;
    int sum = 0;
    for (int i = threadIdx.x; i < 1024; i += 256) {
        int idx = base + i;
        sum += (idx < N_NODES) ? counts[idx] : 0;
    }
    red[threadIdx.x] = sum;
    __syncthreads();
    for (int s = 128; s > 0; s >>= 1) {
        if (threadIdx.x < s) red[threadIdx.x] += red[threadIdx.x + s];
        __syncthreads();
    }
    if (threadIdx.x == 0) blockSums[blockIdx.x] = red[0];
}

__global__ void scan2_kernel(int* __restrict__ blockSums, int nb, int* __restrict__ row_ptr) {
    int run = 0;
    for (int i = 0; i < nb; ++i) { int v = blockSums[i]; blockSums[i] = run; run += v; }
    row_ptr[N_NODES] = run;
}

__global__ void scan3_kernel(const int* __restrict__ counts, const int* __restrict__ blockSums,
                             int* __restrict__ row_ptr, int* __restrict__ cursor,
                             float* __restrict__ deg_inv) {
    __shared__ int lds[256];
    int base = blockIdx.x * 1024;
    int t = threadIdx.x;
    int v[4];
    int s = 0;
    for (int i = 0; i < 4; ++i) {
        int idx = base + t * 4 + i;
        v[i] = (idx < N_NODES) ? counts[idx] : 0;
        s += v[i];
    }
    lds[t] = s;
    __syncthreads();
    for (int off = 1; off < 256; off <<= 1) {
        int add = (t >= off) ? lds[t - off] : 0;
        __syncthreads();
        lds[t] += add;
        __syncthreads();
    }
    int excl = lds[t] - s + blockSums[blockIdx.x];
    for (int i = 0; i < 4; ++i) {
        int idx = base + t * 4 + i;
        if (idx < N_NODES) {
            row_ptr[idx] = excl;
            cursor[idx]  = excl;
            deg_inv[idx] = 1.0f / fmaxf((float)v[i], 1.0f);
            excl += v[i];
        }
    }
}

// ---------------------------------------------------------------------------
// fill v2: XCD-range-partitioned CSR scatter.
// Block b: range r = b&7 (pinned to XCD r by round-robin dispatch),
// slice = b>>3. Scatter target span for range r (~800 KB) stays in XCD r's
// L2 and fills completely -> full-line writebacks (~6.4 MB total, was 105 MB).
// ---------------------------------------------------------------------------
__global__ __launch_bounds__(256) void fill2_kernel(
    const unsigned* __restrict__ e, const int* __restrict__ flag,
    int* __restrict__ cursor, int* __restrict__ csr_src) {
    const int r     = blockIdx.x & (NXCD - 1);
    const int slice = blockIdx.x >> 3;
    const int lo = r * NRANGE;
    const int hi = min(lo + NRANGE, N_NODES);
    const int is64 = *flag;
    const int per = (N_EDGES + NSLICE - 1) / NSLICE;  // 6250
    const int i0 = slice * per;
    const int i1 = min(i0 + per, N_EDGES);
    for (int i = i0 + (int)threadIdx.x; i < i1; i += 256) {
        int d = edge_at(e, (long)N_EDGES + i, is64);
        if (d >= lo && d < hi) {
            int s = edge_at(e, (long)i, is64);
            int pos = atomicAdd(&cursor[d], 1);
            csr_src[pos] = s;
        }
    }
}

// ---------------------------------------------------------------------------
// Weight prep: Bt[layer][n=768][k=128] bf16 = W_hi, column-major (k-contig).
// (2-term split: [x_hi | x_lo] @ [W_hi ; W_hi] — B halves identical, store once.)
// ---------------------------------------------------------------------------
__global__ void bt_prep_kernel(const float* __restrict__ Wl, const float* __restrict__ Wf,
                               const float* __restrict__ Ws, const float* __restrict__ Wfs,
                               __hip_bfloat16* __restrict__ Bt) {
    int idx = blockIdx.x * 256 + threadIdx.x;
    if (idx >= 4 * 768 * 128) return;
    int k   = idx % 128;
    int n   = (idx / 128) % 768;
    int lay = idx / (128 * 768);
    float w;
    if (n < 128)      w = Wl [(size_t)lay * 16384 + k * 128 + n];
    else if (n < 384) w = Wf [(size_t)lay * 32768 + k * 256 + (n - 128)];
    else if (n < 512) w = Ws [(size_t)lay * 16384 + k * 128 + (n - 384)];
    else              w = Wfs[(size_t)lay * 32768 + k * 256 + (n - 512)];
    Bt[idx] = __float2bfloat16(w);
}

// x (f32) -> A planes: A[node][0:128]=hi, A[node][128:256]=lo
__global__ void xsplit_kernel(const float* __restrict__ x, __hip_bfloat16* __restrict__ A) {
    long i = (long)blockIdx.x * 256 + threadIdx.x;
    if (i >= (long)N_NODES * 128) return;
    long node = i >> 7; int c = (int)(i & 127);
    float v = x[i];
    __hip_bfloat16 hi = __float2bfloat16(v);
    A[node * 256 + c]       = hi;
    A[node * 256 + 128 + c] = __float2bfloat16(v - __bfloat162float(hi));
}

// ---------------------------------------------------------------------------
// MFMA GEMM: C[100000 x 768] = A[100000 x 256] @ B[256 x 768]
// A = [x_hi | x_lo] bf16; B = [W_hi ; W_hi] (stored once, k0&64 re-read).
// ---------------------------------------------------------------------------
__global__ __launch_bounds__(256, 2) void mfma_gemm_kernel(
    const __hip_bfloat16* __restrict__ A,
    const __hip_bfloat16* __restrict__ Bt,   // this layer, [768][128]
    const float* __restrict__ bfilm,
    __hip_bfloat16* __restrict__ hbuf,
    __hip_bfloat16* __restrict__ bgbuf,
    float* __restrict__ skp,
    __hip_bfloat16* __restrict__ bsp,
    __hip_bfloat16* __restrict__ gsp)
{
    __shared__ alignas(16) unsigned char lds_raw[32768];
    unsigned char* ldsA = lds_raw;
    unsigned char* ldsB = lds_raw + 16384;

    const int t  = threadIdx.x;
    const int mt = blockIdx.x / 6;
    const int jt = blockIdx.x % 6;
    const long node0 = (long)mt * 128;
    const int w  = t >> 6, l = t & 63;
    const int wm = w >> 1, wn = w & 1;
    const int lr = l & 15;
    const int kq16 = (l >> 4) << 4;
    const int sw = (lr & 7) << 4;

    const int sr  = t >> 3;
    const int scb = (t & 7) << 4;
    const int scbs = scb ^ ((sr & 7) << 4);

    const char* Abase = (const char*)A;
    const char* Bbase = (const char*)Bt + (size_t)(jt * 128) * 256; // row stride 128*2=256B

    f32x4 acc[4][4];
    #pragma unroll
    for (int mi = 0; mi < 4; ++mi)
        #pragma unroll
        for (int ni = 0; ni < 4; ++ni)
            #pragma unroll
            for (int j = 0; j < 4; ++j) acc[mi][ni][j] = 0.f;

    for (int ks = 0; ks < 4; ++ks) {
        const int k0 = ks * 64;            // A logical col (0..255)
        const int kB = k0 & 127;           // B physical col (W_hi stored once)
        #pragma unroll
        for (int i = 0; i < 4; ++i) {
            const int r = (i << 5) + sr;
            gload16(Abase + (node0 + r) * 512 + (size_t)k0 * 2 + scbs,
                    ldsA + (((i << 8) + t) << 4));
            gload16(Bbase + (size_t)r * 256 + (size_t)kB * 2 + scbs,
                    ldsB + (((i << 8) + t) << 4));
        }
        __syncthreads();

        #pragma unroll
        for (int kh = 0; kh < 2; ++kh) {
            const int kbs = ((kh << 6) + kq16) ^ sw;
            bf16x8 af[4], bfr[4];
            #pragma unroll
            for (int mi = 0; mi < 4; ++mi)
                af[mi] = *(const bf16x8*)(ldsA + (wm * 64 + mi * 16 + lr) * 128 + kbs);
            #pragma unroll
            for (int ni = 0; ni < 4; ++ni)
                bfr[ni] = *(const bf16x8*)(ldsB + (wn * 64 + ni * 16 + lr) * 128 + kbs);
            #pragma unroll
            for (int mi = 0; mi < 4; ++mi)
                #pragma unroll
                for (int ni = 0; ni < 4; ++ni)
                    acc[mi][ni] = __builtin_amdgcn_mfma_f32_16x16x32_bf16(
                        af[mi], bfr[ni], acc[mi][ni], 0, 0, 0);
        }
        __syncthreads();
    }

    const int col = lr;
    const int rb  = (l >> 4) << 2;
    if (jt == 0) {
        #pragma unroll
        for (int mi = 0; mi < 4; ++mi)
            #pragma unroll
            for (int ni = 0; ni < 4; ++ni) {
                const int n = wn * 64 + ni * 16 + col;
                #pragma unroll
                for (int j = 0; j < 4; ++j) {
                    long node = node0 + wm * 64 + mi * 16 + rb + j;
                    if (node < N_NODES)
                        hbuf[node * 128 + n] = __float2bfloat16(acc[mi][ni][j]);
                }
            }
    } else if (jt <= 2) {
        const int c0 = (jt - 1) * 128;
        #pragma unroll
        for (int mi = 0; mi < 4; ++mi)
            #pragma unroll
            for (int ni = 0; ni < 4; ++ni) {
                const int n = wn * 64 + ni * 16 + col;
                const float bb = bfilm[c0 + n];
                #pragma unroll
                for (int j = 0; j < 4; ++j) {
                    long node = node0 + wm * 64 + mi * 16 + rb + j;
                    if (node < N_NODES)
                        bgbuf[node * 256 + c0 + n] = __float2bfloat16(acc[mi][ni][j] + bb);
                }
            }
    } else if (jt == 3) {
        #pragma unroll
        for (int mi = 0; mi < 4; ++mi)
            #pragma unroll
            for (int ni = 0; ni < 4; ++ni) {
                const int n = wn * 64 + ni * 16 + col;
                #pragma unroll
                for (int j = 0; j < 4; ++j) {
                    long node = node0 + wm * 64 + mi * 16 + rb + j;
                    if (node < N_NODES)
                        skp[node * 128 + n] = acc[mi][ni][j];
                }
            }
    } else {
        __hip_bfloat16* dst = (jt == 4) ? bsp : gsp;
        #pragma unroll
        for (int mi = 0; mi < 4; ++mi)
            #pragma unroll
            for (int ni = 0; ni < 4; ++ni) {
                const int n = wn * 64 + ni * 16 + col;
                #pragma unroll
                for (int j = 0; j < 4; ++j) {
                    long node = node0 + wm * 64 + mi * 16 + rb + j;
                    if (node < N_NODES)
                        dst[node * 128 + n] = __float2bfloat16(acc[mi][ni][j]);
                }
            }
    }
}

// ---------------------------------------------------------------------------
// Aggregation: 1 wave per node, lane owns cols {2l, 2l+1}; edge loop x4.
// ---------------------------------------------------------------------------
__global__ __launch_bounds__(256) void agg_kernel(
    const unsigned* __restrict__ h2,
    const unsigned* __restrict__ bg2,
    const int* __restrict__ row_ptr, const int* __restrict__ csr_src,
    const float* __restrict__ deg_inv,
    const float* __restrict__ skp,
    const unsigned* __restrict__ bsp2,
    const unsigned* __restrict__ gsp2,
    unsigned* __restrict__ Anext2,
    float* __restrict__ fout, int apply_relu)
{
    const int t = threadIdx.x;
    const int v = blockIdx.x * 4 + (t >> 6);
    const int l = t & 63;

    const float2 beta  = bf2f(bg2[(size_t)v * 128 + l]);
    const float2 gamma = bf2f(bg2[(size_t)v * 128 + 64 + l]);
    const float2 sk = *(const float2*)(skp + (size_t)v * 128 + 2 * l);
    const float2 bs = bf2f(bsp2[(size_t)v * 64 + l]);
    const float2 gs = bf2f(gsp2[(size_t)v * 64 + l]);
    const float dinv = deg_inv[v];

    const int b = row_ptr[v];
    const int e = row_ptr[v + 1];

    float2 a0 = {0.f, 0.f}, a1 = {0.f, 0.f}, a2 = {0.f, 0.f}, a3 = {0.f, 0.f};
    int i = b;
    for (; i + 4 <= e; i += 4) {
        const int s0 = csr_src[i];
        const int s1 = csr_src[i + 1];
        const int s2 = csr_src[i + 2];
        const int s3 = csr_src[i + 3];
        const unsigned p0 = h2[(size_t)s0 * 64 + l];
        const unsigned p1 = h2[(size_t)s1 * 64 + l];
        const unsigned p2 = h2[(size_t)s2 * 64 + l];
        const unsigned p3 = h2[(size_t)s3 * 64 + l];
        float2 h0 = bf2f(p0), h1 = bf2f(p1), h2f = bf2f(p2), h3 = bf2f(p3);
        a0.x += fmaxf(gamma.x * h0.x + beta.x, 0.f);
        a0.y += fmaxf(gamma.y * h0.y + beta.y, 0.f);
        a1.x += fmaxf(gamma.x * h1.x + beta.x, 0.f);
        a1.y += fmaxf(gamma.y * h1.y + beta.y, 0.f);
        a2.x += fmaxf(gamma.x * h2f.x + beta.x, 0.f);
        a2.y += fmaxf(gamma.y * h2f.y + beta.y, 0.f);
        a3.x += fmaxf(gamma.x * h3.x + beta.x, 0.f);
        a3.y += fmaxf(gamma.y * h3.y + beta.y, 0.f);
    }
    for (; i < e; ++i) {
        const int s0 = csr_src[i];
        float2 h0 = bf2f(h2[(size_t)s0 * 64 + l]);
        a0.x += fmaxf(gamma.x * h0.x + beta.x, 0.f);
        a0.y += fmaxf(gamma.y * h0.y + beta.y, 0.f);
    }
    float2 acc;
    acc.x = (a0.x + a1.x) + (a2.x + a3.x);
    acc.y = (a0.y + a1.y) + (a2.y + a3.y);

    float o0 = fmaxf(gs.x * sk.x + bs.x, 0.f) + acc.x * dinv;
    float o1 = fmaxf(gs.y * sk.y + bs.y, 0.f) + acc.y * dinv;
    if (apply_relu) { o0 = fmaxf(o0, 0.f); o1 = fmaxf(o1, 0.f); }

    if (Anext2) {
        unsigned hi = f2bf2(o0, o1);
        float r0, r1;
        { union { unsigned u; float f; } a; a.u = hi << 16;        r0 = o0 - a.f; }
        { union { unsigned u; float f; } a; a.u = hi & 0xffff0000u; r1 = o1 - a.f; }
        Anext2[(size_t)v * 128 + l]      = hi;
        Anext2[(size_t)v * 128 + 64 + l] = f2bf2(r0, r1);
    } else {
        *(float2*)(fout + (size_t)v * 128 + 2 * l) = make_float2(o0, o1);
    }
}

// ---------------------------------------------------------------------------
extern "C" void kernel_launch(void* const* d_in, const int* in_sizes, int n_in,
                              void* d_out, int out_size, void* d_ws, size_t ws_size,
                              hipStream_t stream) {
    const float*    x_in    = (const float*)d_in[0];
    const unsigned* eidx    = (const unsigned*)d_in[1];
    const float*    W_lin   = (const float*)d_in[2];
    const float*    W_film  = (const float*)d_in[3];
    const float*    b_film  = (const float*)d_in[4];
    const float*    W_skip  = (const float*)d_in[5];
    const float*    W_fskip = (const float*)d_in[6];
    float*          out     = (float*)d_out;

    char* ws = (char*)d_ws;
    size_t off = 0;
    auto alloc = [&](size_t bytes) -> void* {
        void* p = ws + off;
        off = (off + bytes + 255) & ~(size_t)255;
        return p;
    };
    int*   flag      = (int*)alloc(4);
    int*   counts    = (int*)alloc((size_t)N_NODES * 4);
    int*   row_ptr   = (int*)alloc((size_t)(N_NODES + 1) * 4);
    int*   cursor    = (int*)alloc((size_t)N_NODES * 4);
    int*   blockSums = (int*)alloc(128 * 4);
    float* deg_inv   = (float*)alloc((size_t)N_NODES * 4);
    int*   csr_src   = (int*)alloc((size_t)N_EDGES * 4);
    __hip_bfloat16* Abuf  = (__hip_bfloat16*)alloc((size_t)N_PAD * 256 * 2);
    __hip_bfloat16* BtAll = (__hip_bfloat16*)alloc((size_t)4 * 768 * 128 * 2);
    __hip_bfloat16* hbuf  = (__hip_bfloat16*)alloc((size_t)N_NODES * 128 * 2);
    __hip_bfloat16* bgbuf = (__hip_bfloat16*)alloc((size_t)N_NODES * 256 * 2);
    __hip_bfloat16* bsp   = (__hip_bfloat16*)alloc((size_t)N_NODES * 128 * 2);
    __hip_bfloat16* gsp   = (__hip_bfloat16*)alloc((size_t)N_NODES * 128 * 2);
    float* skp = out;
    (void)ws_size; (void)in_sizes; (void)n_in; (void)out_size;

    const int NB_SCAN = (N_NODES + 1023) / 1024; // 98
    const int EB = (N_EDGES + 255) / 256;        // 6250

    hipMemsetAsync(counts, 0, (size_t)N_NODES * 4, stream);
    detect_kernel<<<1, 256, 0, stream>>>(eidx, flag);
    hist_kernel<<<EB, 256, 0, stream>>>(eidx, flag, counts);
    scan1_kernel<<<NB_SCAN, 256, 0, stream>>>(counts, blockSums);
    scan2_kernel<<<1, 1, 0, stream>>>(blockSums, NB_SCAN, row_ptr);
    scan3_kernel<<<NB_SCAN, 256, 0, stream>>>(counts, blockSums, row_ptr, cursor, deg_inv);
    fill2_kernel<<<NXCD * NSLICE, 256, 0, stream>>>(eidx, flag, cursor, csr_src);

    xsplit_kernel<<<(N_NODES * 128 + 255) / 256, 256, 0, stream>>>(x_in, Abuf);
    bt_prep_kernel<<<(4 * 768 * 128 + 255) / 256, 256, 0, stream>>>(
        W_lin, W_film, W_skip, W_fskip, BtAll);

    const int MT = N_PAD / 128; // 782
    const int AGG_B = (N_NODES + 3) / 4; // 25000
    for (int l = 0; l < 4; ++l) {
        mfma_gemm_kernel<<<MT * 6, 256, 0, stream>>>(
            Abuf,
            BtAll + (size_t)l * 768 * 128,
            b_film + (size_t)l * 256,
            hbuf, bgbuf, skp, bsp, gsp);
        agg_kernel<<<AGG_B, 256, 0, stream>>>(
            (const unsigned*)hbuf, (const unsigned*)bgbuf,
            row_ptr, csr_src, deg_inv,
            skp, (const unsigned*)bsp, (const unsigned*)gsp,
            (l < 3) ? (unsigned*)Abuf : (unsigned*)nullptr,
            (l == 3) ? out : (float*)nullptr,
            (l < 3) ? 1 : 0);
    }
}

// Round 5
// 713.479 us; speedup vs baseline: 3.2389x; 1.1893x over previous
//
#include <hip/hip_runtime.h>
#include <hip/hip_bf16.h>

#define N_NODES 100000
#define N_PAD   100096   // padded to multiple of 128
#define N_EDGES 1600000
#define NXCD    8
#define NRANGE  ((N_NODES + NXCD - 1) / NXCD)   // 12500
#define NSLICE  256

typedef __bf16 bf16x8 __attribute__((ext_vector_type(8)));
typedef float  f32x4  __attribute__((ext_vector_type(4)));

__device__ __forceinline__ void gload16(const void* g, void* s) {
    __builtin_amdgcn_global_load_lds(
        (const __attribute__((address_space(1))) unsigned int*)g,
        (__attribute__((address_space(3))) unsigned int*)s, 16, 0, 0);
}

// unpack a uint holding two bf16 (lo = element 2l, hi = element 2l+1)
__device__ __forceinline__ float2 bf2f(unsigned p) {
    float2 r;
    union { unsigned u; float f; } a, b;
    a.u = p << 16;
    b.u = p & 0xffff0000u;
    r.x = a.f; r.y = b.f;
    return r;
}
__device__ __forceinline__ unsigned f2bf2(float x, float y) {
    unsigned lo = (unsigned)__builtin_bit_cast(unsigned short, __float2bfloat16(x));
    unsigned hi = (unsigned)__builtin_bit_cast(unsigned short, __float2bfloat16(y));
    return lo | (hi << 16);
}

// ---------------------------------------------------------------------------
// Edge-index width detection (int64 vs int32 layout in the buffer).
// ---------------------------------------------------------------------------
__global__ void detect_kernel(const unsigned* __restrict__ e, int* __restrict__ flag) {
    __shared__ int nz;
    if (threadIdx.x == 0) nz = 0;
    __syncthreads();
    int local = 0;
    for (int i = threadIdx.x; i < 1024; i += blockDim.x)
        if (e[2 * i + 1] != 0) local = 1;
    if (local) atomicOr(&nz, 1);
    __syncthreads();
    if (threadIdx.x == 0) *flag = (nz == 0) ? 1 : 0;
}

__device__ __forceinline__ int edge_at(const unsigned* __restrict__ e, long idx, int is64) {
    return (int)(is64 ? e[2 * idx] : e[idx]);
}

__global__ void hist_kernel(const unsigned* __restrict__ e, const int* __restrict__ flag,
                            int* __restrict__ counts) {
    int i = blockIdx.x * blockDim.x + threadIdx.x;
    if (i >= N_EDGES) return;
    int is64 = *flag;
    int d = edge_at(e, (long)N_EDGES + i, is64);
    atomicAdd(&counts[d], 1);
}

__global__ void scan1_kernel(const int* __restrict__ counts, int* __restrict__ blockSums) {
    __shared__ int red[256];
    int base = blockIdx.x * 1024;
    int sum = 0;
    for (int i = threadIdx.x; i < 1024; i += 256) {
        int idx = base + i;
        sum += (idx < N_NODES) ? counts[idx] : 0;
    }
    red[threadIdx.x] = sum;
    __syncthreads();
    for (int s = 128; s > 0; s >>= 1) {
        if (threadIdx.x < s) red[threadIdx.x] += red[threadIdx.x + s];
        __syncthreads();
    }
    if (threadIdx.x == 0) blockSums[blockIdx.x] = red[0];
}

__global__ void scan2_kernel(int* __restrict__ blockSums, int nb, int* __restrict__ row_ptr) {
    int run = 0;
    for (int i = 0; i < nb; ++i) { int v = blockSums[i]; blockSums[i] = run; run += v; }
    row_ptr[N_NODES] = run;
}

__global__ void scan3_kernel(const int* __restrict__ counts, const int* __restrict__ blockSums,
                             int* __restrict__ row_ptr, int* __restrict__ cursor,
                             float* __restrict__ deg_inv) {
    __shared__ int lds[256];
    int base = blockIdx.x * 1024;
    int t = threadIdx.x;
    int v[4];
    int s = 0;
    for (int i = 0; i < 4; ++i) {
        int idx = base + t * 4 + i;
        v[i] = (idx < N_NODES) ? counts[idx] : 0;
        s += v[i];
    }
    lds[t] = s;
    __syncthreads();
    for (int off = 1; off < 256; off <<= 1) {
        int add = (t >= off) ? lds[t - off] : 0;
        __syncthreads();
        lds[t] += add;
        __syncthreads();
    }
    int excl = lds[t] - s + blockSums[blockIdx.x];
    for (int i = 0; i < 4; ++i) {
        int idx = base + t * 4 + i;
        if (idx < N_NODES) {
            row_ptr[idx] = excl;
            cursor[idx]  = excl;
            deg_inv[idx] = 1.0f / fmaxf((float)v[i], 1.0f);
            excl += v[i];
        }
    }
}

// ---------------------------------------------------------------------------
// fill v2: XCD-range-partitioned CSR scatter (full-line writebacks in one L2).
// ---------------------------------------------------------------------------
__global__ __launch_bounds__(256) void fill2_kernel(
    const unsigned* __restrict__ e, const int* __restrict__ flag,
    int* __restrict__ cursor, int* __restrict__ csr_src) {
    const int r     = blockIdx.x & (NXCD - 1);
    const int slice = blockIdx.x >> 3;
    const int lo = r * NRANGE;
    const int hi = min(lo + NRANGE, N_NODES);
    const int is64 = *flag;
    const int per = (N_EDGES + NSLICE - 1) / NSLICE;  // 6250
    const int i0 = slice * per;
    const int i1 = min(i0 + per, N_EDGES);
    for (int i = i0 + (int)threadIdx.x; i < i1; i += 256) {
        int d = edge_at(e, (long)N_EDGES + i, is64);
        if (d >= lo && d < hi) {
            int s = edge_at(e, (long)i, is64);
            int pos = atomicAdd(&cursor[d], 1);
            csr_src[pos] = s;
        }
    }
}

// ---------------------------------------------------------------------------
// Weight prep: BtAll[layer][768 rows][128 k] bf16, k-contiguous.
// Rows 0..383   (main):  n<128 -> W_lin col n ; n<384 -> W_film col n-128.
// Rows 384..767 (skip, PERMUTED in groups of 16):
//   rr = row-384, g = rr/16, within = rr%16, kind = g%3, c = (g/3)*16+within
//   kind 0 -> W_skip[:,c]; 1 -> W_fskip[:,c] (beta_s); 2 -> W_fskip[:,128+c] (gamma_s)
// ---------------------------------------------------------------------------
__global__ void bt_prep_kernel(const float* __restrict__ Wl, const float* __restrict__ Wf,
                               const float* __restrict__ Ws, const float* __restrict__ Wfs,
                               __hip_bfloat16* __restrict__ Bt) {
    int idx = blockIdx.x * 256 + threadIdx.x;
    if (idx >= 4 * 768 * 128) return;
    int k   = idx % 128;
    int row = (idx / 128) % 768;
    int lay = idx / (128 * 768);
    float w;
    if (row < 128) {
        w = Wl[(size_t)lay * 16384 + k * 128 + row];
    } else if (row < 384) {
        w = Wf[(size_t)lay * 32768 + k * 256 + (row - 128)];
    } else {
        int rr = row - 384;
        int g = rr >> 4, within = rr & 15;
        int kind = g % 3;
        int c = (g / 3) * 16 + within;
        if (kind == 0)      w = Ws [(size_t)lay * 16384 + k * 128 + c];
        else if (kind == 1) w = Wfs[(size_t)lay * 32768 + k * 256 + c];
        else                w = Wfs[(size_t)lay * 32768 + k * 256 + 128 + c];
    }
    Bt[idx] = __float2bfloat16(w);
}

// x (f32) -> A bf16 [node][128] (packed pairs)
__global__ void cast_kernel(const float* __restrict__ x, unsigned* __restrict__ A2) {
    long i = (long)blockIdx.x * 256 + threadIdx.x;
    if (i >= (long)N_NODES * 64) return;
    float2 v = ((const float2*)x)[i];
    A2[i] = f2bf2(v.x, v.y);
}

// ---------------------------------------------------------------------------
// Main MFMA GEMM: [h | beta | gamma] = A[N_PAD x 128] @ B[128 x 384]
// Grid: mt x 3 n-tiles. Block 256 thr = 4 waves (2x2), 64x64/wave.
// ---------------------------------------------------------------------------
__global__ __launch_bounds__(256, 2) void mfma_gemm_kernel(
    const __hip_bfloat16* __restrict__ A,
    const __hip_bfloat16* __restrict__ Bt,   // this layer, rows 0..383
    const float* __restrict__ bfilm,
    __hip_bfloat16* __restrict__ hbuf,       // [N][128]
    __hip_bfloat16* __restrict__ bgbuf)      // [N][256]
{
    __shared__ alignas(16) unsigned char lds_raw[32768];
    unsigned char* ldsA = lds_raw;
    unsigned char* ldsB = lds_raw + 16384;

    const int t  = threadIdx.x;
    const int mt = blockIdx.x / 3;
    const int jt = blockIdx.x % 3;
    const long node0 = (long)mt * 128;
    const int w  = t >> 6, l = t & 63;
    const int wm = w >> 1, wn = w & 1;
    const int lr = l & 15;
    const int kq16 = (l >> 4) << 4;
    const int sw = (lr & 7) << 4;

    const int sr  = t >> 3;
    const int scb = (t & 7) << 4;
    const int scbs = scb ^ ((sr & 7) << 4);

    const char* Abase = (const char*)A;
    const char* Bbase = (const char*)Bt + (size_t)(jt * 128) * 256; // row stride 128*2B

    f32x4 acc[4][4];
    #pragma unroll
    for (int mi = 0; mi < 4; ++mi)
        #pragma unroll
        for (int ni = 0; ni < 4; ++ni)
            #pragma unroll
            for (int j = 0; j < 4; ++j) acc[mi][ni][j] = 0.f;

    #pragma unroll
    for (int ks = 0; ks < 2; ++ks) {
        const int k0 = ks * 64;
        #pragma unroll
        for (int i = 0; i < 4; ++i) {
            const int r = (i << 5) + sr;
            gload16(Abase + (node0 + r) * 256 + (size_t)k0 * 2 + scbs,
                    ldsA + (((i << 8) + t) << 4));
            gload16(Bbase + (size_t)r * 256 + (size_t)k0 * 2 + scbs,
                    ldsB + (((i << 8) + t) << 4));
        }
        __syncthreads();

        #pragma unroll
        for (int kh = 0; kh < 2; ++kh) {
            const int kbs = ((kh << 6) + kq16) ^ sw;
            bf16x8 af[4], bfr[4];
            #pragma unroll
            for (int mi = 0; mi < 4; ++mi)
                af[mi] = *(const bf16x8*)(ldsA + (wm * 64 + mi * 16 + lr) * 128 + kbs);
            #pragma unroll
            for (int ni = 0; ni < 4; ++ni)
                bfr[ni] = *(const bf16x8*)(ldsB + (wn * 64 + ni * 16 + lr) * 128 + kbs);
            #pragma unroll
            for (int mi = 0; mi < 4; ++mi)
                #pragma unroll
                for (int ni = 0; ni < 4; ++ni)
                    acc[mi][ni] = __builtin_amdgcn_mfma_f32_16x16x32_bf16(
                        af[mi], bfr[ni], acc[mi][ni], 0, 0, 0);
        }
        __syncthreads();
    }

    // epilogue: C/D layout col=lane&15, row=(lane>>4)*4+j
    const int col = lr;
    const int rb  = (l >> 4) << 2;
    if (jt == 0) {
        #pragma unroll
        for (int mi = 0; mi < 4; ++mi)
            #pragma unroll
            for (int ni = 0; ni < 4; ++ni) {
                const int n = wn * 64 + ni * 16 + col;
                #pragma unroll
                for (int j = 0; j < 4; ++j) {
                    long node = node0 + wm * 64 + mi * 16 + rb + j;
                    if (node < N_NODES)
                        hbuf[node * 128 + n] = __float2bfloat16(acc[mi][ni][j]);
                }
            }
    } else {
        const int c0 = (jt - 1) * 128;
        #pragma unroll
        for (int mi = 0; mi < 4; ++mi)
            #pragma unroll
            for (int ni = 0; ni < 4; ++ni) {
                const int n = wn * 64 + ni * 16 + col;
                const float bb = bfilm[c0 + n];
                #pragma unroll
                for (int j = 0; j < 4; ++j) {
                    long node = node0 + wm * 64 + mi * 16 + rb + j;
                    if (node < N_NODES)
                        bgbuf[node * 256 + c0 + n] = __float2bfloat16(acc[mi][ni][j] + bb);
                }
            }
    }
}

// ---------------------------------------------------------------------------
// Skip-path GEMM with fused FiLM epilogue:
//   computes sk, bs, gs (permuted B rows 384..767) and writes
//   skb[node][c] = relu(gs*sk + bs)  (f32, = d_out plane)
// Tile: 128m x 96n, 4 waves (2m x 2n), wave = 64m x 48n = one (sk,bs,gs) triple.
// ---------------------------------------------------------------------------
__global__ __launch_bounds__(256, 2) void skip_gemm_kernel(
    const __hip_bfloat16* __restrict__ A,
    const __hip_bfloat16* __restrict__ Bs,   // this layer, rows 384..767 base
    float* __restrict__ skb)
{
    __shared__ alignas(16) unsigned char lds_raw[16384 + 12288];
    unsigned char* ldsA = lds_raw;
    unsigned char* ldsB = lds_raw + 16384;

    const int t  = threadIdx.x;
    const int mt = blockIdx.x >> 2;
    const int jt2 = blockIdx.x & 3;
    const long node0 = (long)mt * 128;
    const int w  = t >> 6, l = t & 63;
    const int wm = w >> 1, wn = w & 1;
    const int lr = l & 15;
    const int kq16 = (l >> 4) << 4;
    const int sw = (lr & 7) << 4;

    const int sr  = t >> 3;
    const int scb = (t & 7) << 4;
    const int scbs = scb ^ ((sr & 7) << 4);

    const char* Abase = (const char*)A;
    const char* Bbase = (const char*)Bs + (size_t)(jt2 * 96) * 256;

    f32x4 acc[4][3];
    #pragma unroll
    for (int mi = 0; mi < 4; ++mi)
        #pragma unroll
        for (int ni = 0; ni < 3; ++ni)
            #pragma unroll
            for (int j = 0; j < 4; ++j) acc[mi][ni][j] = 0.f;

    #pragma unroll
    for (int ks = 0; ks < 2; ++ks) {
        const int k0 = ks * 64;
        #pragma unroll
        for (int i = 0; i < 4; ++i) {
            const int r = (i << 5) + sr;
            gload16(Abase + (node0 + r) * 256 + (size_t)k0 * 2 + scbs,
                    ldsA + (((i << 8) + t) << 4));
        }
        #pragma unroll
        for (int i = 0; i < 3; ++i) {
            const int r = (i << 5) + sr;
            gload16(Bbase + (size_t)r * 256 + (size_t)k0 * 2 + scbs,
                    ldsB + (((i << 8) + t) << 4));
        }
        __syncthreads();

        #pragma unroll
        for (int kh = 0; kh < 2; ++kh) {
            const int kbs = ((kh << 6) + kq16) ^ sw;
            bf16x8 af[4], bfr[3];
            #pragma unroll
            for (int mi = 0; mi < 4; ++mi)
                af[mi] = *(const bf16x8*)(ldsA + (wm * 64 + mi * 16 + lr) * 128 + kbs);
            #pragma unroll
            for (int ni = 0; ni < 3; ++ni)
                bfr[ni] = *(const bf16x8*)(ldsB + (wn * 48 + ni * 16 + lr) * 128 + kbs);
            #pragma unroll
            for (int mi = 0; mi < 4; ++mi)
                #pragma unroll
                for (int ni = 0; ni < 3; ++ni)
                    acc[mi][ni] = __builtin_amdgcn_mfma_f32_16x16x32_bf16(
                        af[mi], bfr[ni], acc[mi][ni], 0, 0, 0);
        }
        __syncthreads();
    }

    // fused epilogue: ni 0=sk, 1=bs, 2=gs for the SAME column c
    const int c  = (2 * jt2 + wn) * 16 + lr;
    const int rb = (l >> 4) << 2;
    #pragma unroll
    for (int mi = 0; mi < 4; ++mi)
        #pragma unroll
        for (int j = 0; j < 4; ++j) {
            long node = node0 + wm * 64 + mi * 16 + rb + j;
            if (node < N_NODES) {
                float o = fmaxf(acc[mi][2][j] * acc[mi][0][j] + acc[mi][1][j], 0.f);
                skb[node * 128 + c] = o;
            }
        }
}

// ---------------------------------------------------------------------------
// Aggregation: 1 wave per node, lane owns cols {2l, 2l+1}; edge loop x4.
// o = skb (pre-relu'd skip) + deg_inv * sum relu(gamma*h[s]+beta)
// ---------------------------------------------------------------------------
__global__ __launch_bounds__(256) void agg_kernel(
    const unsigned* __restrict__ h2,
    const unsigned* __restrict__ bg2,
    const int* __restrict__ row_ptr, const int* __restrict__ csr_src,
    const float* __restrict__ deg_inv,
    const float* __restrict__ skb,
    unsigned* __restrict__ Anext2,
    float* __restrict__ fout)
{
    const int t = threadIdx.x;
    const int v = blockIdx.x * 4 + (t >> 6);
    const int l = t & 63;

    const float2 beta  = bf2f(bg2[(size_t)v * 128 + l]);
    const float2 gamma = bf2f(bg2[(size_t)v * 128 + 64 + l]);
    const float2 sk = *(const float2*)(skb + (size_t)v * 128 + 2 * l);
    const float dinv = deg_inv[v];

    const int b = row_ptr[v];
    const int e = row_ptr[v + 1];

    float2 a0 = {0.f, 0.f}, a1 = {0.f, 0.f}, a2 = {0.f, 0.f}, a3 = {0.f, 0.f};
    int i = b;
    for (; i + 4 <= e; i += 4) {
        const int s0 = csr_src[i];
        const int s1 = csr_src[i + 1];
        const int s2 = csr_src[i + 2];
        const int s3 = csr_src[i + 3];
        const unsigned p0 = h2[(size_t)s0 * 64 + l];
        const unsigned p1 = h2[(size_t)s1 * 64 + l];
        const unsigned p2 = h2[(size_t)s2 * 64 + l];
        const unsigned p3 = h2[(size_t)s3 * 64 + l];
        float2 h0 = bf2f(p0), h1 = bf2f(p1), h2f = bf2f(p2), h3 = bf2f(p3);
        a0.x += fmaxf(gamma.x * h0.x + beta.x, 0.f);
        a0.y += fmaxf(gamma.y * h0.y + beta.y, 0.f);
        a1.x += fmaxf(gamma.x * h1.x + beta.x, 0.f);
        a1.y += fmaxf(gamma.y * h1.y + beta.y, 0.f);
        a2.x += fmaxf(gamma.x * h2f.x + beta.x, 0.f);
        a2.y += fmaxf(gamma.y * h2f.y + beta.y, 0.f);
        a3.x += fmaxf(gamma.x * h3.x + beta.x, 0.f);
        a3.y += fmaxf(gamma.y * h3.y + beta.y, 0.f);
    }
    for (; i < e; ++i) {
        const int s0 = csr_src[i];
        float2 h0 = bf2f(h2[(size_t)s0 * 64 + l]);
        a0.x += fmaxf(gamma.x * h0.x + beta.x, 0.f);
        a0.y += fmaxf(gamma.y * h0.y + beta.y, 0.f);
    }
    float2 acc;
    acc.x = (a0.x + a1.x) + (a2.x + a3.x);
    acc.y = (a0.y + a1.y) + (a2.y + a3.y);

    // skip term already relu'd; both terms >= 0 so inter-layer relu is a no-op
    float o0 = sk.x + acc.x * dinv;
    float o1 = sk.y + acc.y * dinv;

    if (Anext2) {
        Anext2[(size_t)v * 64 + l] = f2bf2(o0, o1);
    } else {
        *(float2*)(fout + (size_t)v * 128 + 2 * l) = make_float2(o0, o1);
    }
}

// ---------------------------------------------------------------------------
extern "C" void kernel_launch(void* const* d_in, const int* in_sizes, int n_in,
                              void* d_out, int out_size, void* d_ws, size_t ws_size,
                              hipStream_t stream) {
    const float*    x_in    = (const float*)d_in[0];
    const unsigned* eidx    = (const unsigned*)d_in[1];
    const float*    W_lin   = (const float*)d_in[2];
    const float*    W_film  = (const float*)d_in[3];
    const float*    b_film  = (const float*)d_in[4];
    const float*    W_skip  = (const float*)d_in[5];
    const float*    W_fskip = (const float*)d_in[6];
    float*          out     = (float*)d_out;

    char* ws = (char*)d_ws;
    size_t off = 0;
    auto alloc = [&](size_t bytes) -> void* {
        void* p = ws + off;
        off = (off + bytes + 255) & ~(size_t)255;
        return p;
    };
    int*   flag      = (int*)alloc(4);
    int*   counts    = (int*)alloc((size_t)N_NODES * 4);
    int*   row_ptr   = (int*)alloc((size_t)(N_NODES + 1) * 4);
    int*   cursor    = (int*)alloc((size_t)N_NODES * 4);
    int*   blockSums = (int*)alloc(128 * 4);
    float* deg_inv   = (float*)alloc((size_t)N_NODES * 4);
    int*   csr_src   = (int*)alloc((size_t)N_EDGES * 4);
    __hip_bfloat16* Abuf  = (__hip_bfloat16*)alloc((size_t)N_PAD * 128 * 2);
    __hip_bfloat16* BtAll = (__hip_bfloat16*)alloc((size_t)4 * 768 * 128 * 2);
    __hip_bfloat16* hbuf  = (__hip_bfloat16*)alloc((size_t)N_NODES * 128 * 2);
    __hip_bfloat16* bgbuf = (__hip_bfloat16*)alloc((size_t)N_NODES * 256 * 2);
    float* skb = out;  // d_out doubles as the f32 fused-skip plane
    (void)ws_size; (void)in_sizes; (void)n_in; (void)out_size;

    const int NB_SCAN = (N_NODES + 1023) / 1024; // 98
    const int EB = (N_EDGES + 255) / 256;        // 6250

    hipMemsetAsync(counts, 0, (size_t)N_NODES * 4, stream);
    detect_kernel<<<1, 256, 0, stream>>>(eidx, flag);
    hist_kernel<<<EB, 256, 0, stream>>>(eidx, flag, counts);
    scan1_kernel<<<NB_SCAN, 256, 0, stream>>>(counts, blockSums);
    scan2_kernel<<<1, 1, 0, stream>>>(blockSums, NB_SCAN, row_ptr);
    scan3_kernel<<<NB_SCAN, 256, 0, stream>>>(counts, blockSums, row_ptr, cursor, deg_inv);
    fill2_kernel<<<NXCD * NSLICE, 256, 0, stream>>>(eidx, flag, cursor, csr_src);

    cast_kernel<<<(N_NODES * 64 + 255) / 256, 256, 0, stream>>>(x_in, (unsigned*)Abuf);
    bt_prep_kernel<<<(4 * 768 * 128 + 255) / 256, 256, 0, stream>>>(
        W_lin, W_film, W_skip, W_fskip, BtAll);

    const int MT = N_PAD / 128; // 782
    const int AGG_B = (N_NODES + 3) / 4; // 25000
    for (int l = 0; l < 4; ++l) {
        const __hip_bfloat16* Bt_l = BtAll + (size_t)l * 768 * 128;
        mfma_gemm_kernel<<<MT * 3, 256, 0, stream>>>(
            Abuf, Bt_l, b_film + (size_t)l * 256, hbuf, bgbuf);
        skip_gemm_kernel<<<MT * 4, 256, 0, stream>>>(
            Abuf, Bt_l + (size_t)384 * 128, skb);
        agg_kernel<<<AGG_B, 256, 0, stream>>>(
            (const unsigned*)hbuf, (const unsigned*)bgbuf,
            row_ptr, csr_src, deg_inv, skb,
            (l < 3) ? (unsigned*)Abuf : (unsigned*)nullptr,
            (l == 3) ? out : (float*)nullptr);
    }
}

// Round 6
// 659.199 us; speedup vs baseline: 3.5056x; 1.0823x over previous
//
#include <hip/hip_runtime.h>
#include <hip/hip_bf16.h>

#define N_NODES 100000
#define N_PAD   100096   // padded to multiple of 128
#define N_EDGES 1600000
#define NXCD    8
#define NRANGE  ((N_NODES + NXCD - 1) / NXCD)   // 12500
#define NSLICE  256

typedef __bf16 bf16x8 __attribute__((ext_vector_type(8)));
typedef float  f32x4  __attribute__((ext_vector_type(4)));

__device__ __forceinline__ void gload16(const void* g, void* s) {
    __builtin_amdgcn_global_load_lds(
        (const __attribute__((address_space(1))) unsigned int*)g,
        (__attribute__((address_space(3))) unsigned int*)s, 16, 0, 0);
}

// unpack a uint holding two bf16 (x = low ushort = even col, y = high = odd col)
__device__ __forceinline__ float2 bf2f(unsigned p) {
    float2 r;
    union { unsigned u; float f; } a, b;
    a.u = p << 16;
    b.u = p & 0xffff0000u;
    r.x = a.f; r.y = b.f;
    return r;
}
__device__ __forceinline__ unsigned f2bf2(float x, float y) {
    unsigned lo = (unsigned)__builtin_bit_cast(unsigned short, __float2bfloat16(x));
    unsigned hi = (unsigned)__builtin_bit_cast(unsigned short, __float2bfloat16(y));
    return lo | (hi << 16);
}

// ---------------------------------------------------------------------------
// Edge-index width detection (int64 vs int32 layout in the buffer).
// ---------------------------------------------------------------------------
__global__ void detect_kernel(const unsigned* __restrict__ e, int* __restrict__ flag) {
    __shared__ int nz;
    if (threadIdx.x == 0) nz = 0;
    __syncthreads();
    int local = 0;
    for (int i = threadIdx.x; i < 1024; i += blockDim.x)
        if (e[2 * i + 1] != 0) local = 1;
    if (local) atomicOr(&nz, 1);
    __syncthreads();
    if (threadIdx.x == 0) *flag = (nz == 0) ? 1 : 0;
}

__device__ __forceinline__ int edge_at(const unsigned* __restrict__ e, long idx, int is64) {
    return (int)(is64 ? e[2 * idx] : e[idx]);
}

__global__ void hist_kernel(const unsigned* __restrict__ e, const int* __restrict__ flag,
                            int* __restrict__ counts) {
    int i = blockIdx.x * blockDim.x + threadIdx.x;
    if (i >= N_EDGES) return;
    int is64 = *flag;
    int d = edge_at(e, (long)N_EDGES + i, is64);
    atomicAdd(&counts[d], 1);
}

__global__ void scan1_kernel(const int* __restrict__ counts, int* __restrict__ blockSums) {
    __shared__ int red[256];
    int base = blockIdx.x * 1024;
    int sum = 0;
    for (int i = threadIdx.x; i < 1024; i += 256) {
        int idx = base + i;
        sum += (idx < N_NODES) ? counts[idx] : 0;
    }
    red[threadIdx.x] = sum;
    __syncthreads();
    for (int s = 128; s > 0; s >>= 1) {
        if (threadIdx.x < s) red[threadIdx.x] += red[threadIdx.x + s];
        __syncthreads();
    }
    if (threadIdx.x == 0) blockSums[blockIdx.x] = red[0];
}

__global__ void scan2_kernel(int* __restrict__ blockSums, int nb, int* __restrict__ row_ptr) {
    int run = 0;
    for (int i = 0; i < nb; ++i) { int v = blockSums[i]; blockSums[i] = run; run += v; }
    row_ptr[N_NODES] = run;
}

__global__ void scan3_kernel(const int* __restrict__ counts, const int* __restrict__ blockSums,
                             int* __restrict__ row_ptr, int* __restrict__ cursor,
                             float* __restrict__ deg_inv) {
    __shared__ int lds[256];
    int base = blockIdx.x * 1024;
    int t = threadIdx.x;
    int v[4];
    int s = 0;
    for (int i = 0; i < 4; ++i) {
        int idx = base + t * 4 + i;
        v[i] = (idx < N_NODES) ? counts[idx] : 0;
        s += v[i];
    }
    lds[t] = s;
    __syncthreads();
    for (int off = 1; off < 256; off <<= 1) {
        int add = (t >= off) ? lds[t - off] : 0;
        __syncthreads();
        lds[t] += add;
        __syncthreads();
    }
    int excl = lds[t] - s + blockSums[blockIdx.x];
    for (int i = 0; i < 4; ++i) {
        int idx = base + t * 4 + i;
        if (idx < N_NODES) {
            row_ptr[idx] = excl;
            cursor[idx]  = excl;
            deg_inv[idx] = 1.0f / fmaxf((float)v[i], 1.0f);
            excl += v[i];
        }
    }
}

// ---------------------------------------------------------------------------
// fill v2: XCD-range-partitioned CSR scatter (full-line writebacks in one L2).
// ---------------------------------------------------------------------------
__global__ __launch_bounds__(256) void fill2_kernel(
    const unsigned* __restrict__ e, const int* __restrict__ flag,
    int* __restrict__ cursor, int* __restrict__ csr_src) {
    const int r     = blockIdx.x & (NXCD - 1);
    const int slice = blockIdx.x >> 3;
    const int lo = r * NRANGE;
    const int hi = min(lo + NRANGE, N_NODES);
    const int is64 = *flag;
    const int per = (N_EDGES + NSLICE - 1) / NSLICE;  // 6250
    const int i0 = slice * per;
    const int i1 = min(i0 + per, N_EDGES);
    for (int i = i0 + (int)threadIdx.x; i < i1; i += 256) {
        int d = edge_at(e, (long)N_EDGES + i, is64);
        if (d >= lo && d < hi) {
            int s = edge_at(e, (long)i, is64);
            int pos = atomicAdd(&cursor[d], 1);
            csr_src[pos] = s;
        }
    }
}

// ---------------------------------------------------------------------------
// Weight prep: BtAll[layer][768 rows][128 k] bf16, k-contiguous.
// Rows 0..383   (main):  n<128 -> W_lin col n ; n<384 -> W_film col n-128.
// Rows 384..767 (skip, PERMUTED in groups of 16):
//   rr=row-384, g=rr/16, within=rr%16, kind=g%3, c=(g/3)*16+within
//   kind 0 -> W_skip[:,c]; 1 -> W_fskip[:,c] (beta_s); 2 -> W_fskip[:,128+c] (gamma_s)
// ---------------------------------------------------------------------------
__global__ void bt_prep_kernel(const float* __restrict__ Wl, const float* __restrict__ Wf,
                               const float* __restrict__ Ws, const float* __restrict__ Wfs,
                               __hip_bfloat16* __restrict__ Bt) {
    int idx = blockIdx.x * 256 + threadIdx.x;
    if (idx >= 4 * 768 * 128) return;
    int k   = idx % 128;
    int row = (idx / 128) % 768;
    int lay = idx / (128 * 768);
    float w;
    if (row < 128) {
        w = Wl[(size_t)lay * 16384 + k * 128 + row];
    } else if (row < 384) {
        w = Wf[(size_t)lay * 32768 + k * 256 + (row - 128)];
    } else {
        int rr = row - 384;
        int g = rr >> 4, within = rr & 15;
        int kind = g % 3;
        int c = (g / 3) * 16 + within;
        if (kind == 0)      w = Ws [(size_t)lay * 16384 + k * 128 + c];
        else if (kind == 1) w = Wfs[(size_t)lay * 32768 + k * 256 + c];
        else                w = Wfs[(size_t)lay * 32768 + k * 256 + 128 + c];
    }
    Bt[idx] = __float2bfloat16(w);
}

// x (f32) -> A bf16 [node][128] (packed pairs)
__global__ void cast_kernel(const float* __restrict__ x, unsigned* __restrict__ A2) {
    long i = (long)blockIdx.x * 256 + threadIdx.x;
    if (i >= (long)N_NODES * 64) return;
    float2 v = ((const float2*)x)[i];
    A2[i] = f2bf2(v.x, v.y);
}

// ---------------------------------------------------------------------------
// Fused MFMA GEMM (main + skip paths in one launch, grid = MT x 7):
//  jt 0..2 : [h | beta | gamma] = A @ B rows 0..383   (128-wide n-tiles)
//  jt 3..6 : skb[node][c] = relu(gs*sk+bs) via permuted B rows 384..767
//            (96-wide n-tiles; wave = one (sk,bs,gs) triple), written bf16.
// ---------------------------------------------------------------------------
__global__ __launch_bounds__(256, 2) void fused_gemm_kernel(
    const __hip_bfloat16* __restrict__ A,
    const __hip_bfloat16* __restrict__ Bt,   // this layer, all 768 rows
    const float* __restrict__ bfilm,
    __hip_bfloat16* __restrict__ hbuf,       // [N][128]
    __hip_bfloat16* __restrict__ bgbuf,      // [N][256]
    __hip_bfloat16* __restrict__ skbh)       // [N][128] bf16 (relu'd skip)
{
    __shared__ alignas(16) unsigned char lds_raw[32768];
    unsigned char* ldsA = lds_raw;
    unsigned char* ldsB = lds_raw + 16384;

    const int t  = threadIdx.x;
    const int mt = blockIdx.x / 7;
    const int jt = blockIdx.x % 7;
    const long node0 = (long)mt * 128;
    const int w  = t >> 6, l = t & 63;
    const int wm = w >> 1, wn = w & 1;
    const int lr = l & 15;
    const int kq16 = (l >> 4) << 4;
    const int sw = (lr & 7) << 4;

    const int sr  = t >> 3;
    const int scb = (t & 7) << 4;
    const int scbs = scb ^ ((sr & 7) << 4);

    const char* Abase = (const char*)A;

    if (jt < 3) {
        // ------------------- main path: 128-wide n-tile -------------------
        const char* Bbase = (const char*)Bt + (size_t)(jt * 128) * 256;
        f32x4 acc[4][4];
        #pragma unroll
        for (int mi = 0; mi < 4; ++mi)
            #pragma unroll
            for (int ni = 0; ni < 4; ++ni)
                #pragma unroll
                for (int j = 0; j < 4; ++j) acc[mi][ni][j] = 0.f;

        #pragma unroll
        for (int ks = 0; ks < 2; ++ks) {
            const int k0 = ks * 64;
            #pragma unroll
            for (int i = 0; i < 4; ++i) {
                const int r = (i << 5) + sr;
                gload16(Abase + (node0 + r) * 256 + (size_t)k0 * 2 + scbs,
                        ldsA + (((i << 8) + t) << 4));
                gload16(Bbase + (size_t)r * 256 + (size_t)k0 * 2 + scbs,
                        ldsB + (((i << 8) + t) << 4));
            }
            __syncthreads();

            #pragma unroll
            for (int kh = 0; kh < 2; ++kh) {
                const int kbs = ((kh << 6) + kq16) ^ sw;
                bf16x8 af[4], bfr[4];
                #pragma unroll
                for (int mi = 0; mi < 4; ++mi)
                    af[mi] = *(const bf16x8*)(ldsA + (wm * 64 + mi * 16 + lr) * 128 + kbs);
                #pragma unroll
                for (int ni = 0; ni < 4; ++ni)
                    bfr[ni] = *(const bf16x8*)(ldsB + (wn * 64 + ni * 16 + lr) * 128 + kbs);
                #pragma unroll
                for (int mi = 0; mi < 4; ++mi)
                    #pragma unroll
                    for (int ni = 0; ni < 4; ++ni)
                        acc[mi][ni] = __builtin_amdgcn_mfma_f32_16x16x32_bf16(
                            af[mi], bfr[ni], acc[mi][ni], 0, 0, 0);
            }
            __syncthreads();
        }

        const int col = lr;
        const int rb  = (l >> 4) << 2;
        if (jt == 0) {
            #pragma unroll
            for (int mi = 0; mi < 4; ++mi)
                #pragma unroll
                for (int ni = 0; ni < 4; ++ni) {
                    const int n = wn * 64 + ni * 16 + col;
                    #pragma unroll
                    for (int j = 0; j < 4; ++j) {
                        long node = node0 + wm * 64 + mi * 16 + rb + j;
                        if (node < N_NODES)
                            hbuf[node * 128 + n] = __float2bfloat16(acc[mi][ni][j]);
                    }
                }
        } else {
            const int c0 = (jt - 1) * 128;
            #pragma unroll
            for (int mi = 0; mi < 4; ++mi)
                #pragma unroll
                for (int ni = 0; ni < 4; ++ni) {
                    const int n = wn * 64 + ni * 16 + col;
                    const float bb = bfilm[c0 + n];
                    #pragma unroll
                    for (int j = 0; j < 4; ++j) {
                        long node = node0 + wm * 64 + mi * 16 + rb + j;
                        if (node < N_NODES)
                            bgbuf[node * 256 + c0 + n] = __float2bfloat16(acc[mi][ni][j] + bb);
                    }
                }
        }
    } else {
        // ------------------- skip path: 96-wide n-tile --------------------
        const int jt2 = jt - 3;
        const char* Bbase = (const char*)Bt + (size_t)(384 + jt2 * 96) * 256;
        f32x4 acc[4][3];
        #pragma unroll
        for (int mi = 0; mi < 4; ++mi)
            #pragma unroll
            for (int ni = 0; ni < 3; ++ni)
                #pragma unroll
                for (int j = 0; j < 4; ++j) acc[mi][ni][j] = 0.f;

        #pragma unroll
        for (int ks = 0; ks < 2; ++ks) {
            const int k0 = ks * 64;
            #pragma unroll
            for (int i = 0; i < 4; ++i) {
                const int r = (i << 5) + sr;
                gload16(Abase + (node0 + r) * 256 + (size_t)k0 * 2 + scbs,
                        ldsA + (((i << 8) + t) << 4));
            }
            #pragma unroll
            for (int i = 0; i < 3; ++i) {
                const int r = (i << 5) + sr;
                gload16(Bbase + (size_t)r * 256 + (size_t)k0 * 2 + scbs,
                        ldsB + (((i << 8) + t) << 4));
            }
            __syncthreads();

            #pragma unroll
            for (int kh = 0; kh < 2; ++kh) {
                const int kbs = ((kh << 6) + kq16) ^ sw;
                bf16x8 af[4], bfr[3];
                #pragma unroll
                for (int mi = 0; mi < 4; ++mi)
                    af[mi] = *(const bf16x8*)(ldsA + (wm * 64 + mi * 16 + lr) * 128 + kbs);
                #pragma unroll
                for (int ni = 0; ni < 3; ++ni)
                    bfr[ni] = *(const bf16x8*)(ldsB + (wn * 48 + ni * 16 + lr) * 128 + kbs);
                #pragma unroll
                for (int mi = 0; mi < 4; ++mi)
                    #pragma unroll
                    for (int ni = 0; ni < 3; ++ni)
                        acc[mi][ni] = __builtin_amdgcn_mfma_f32_16x16x32_bf16(
                            af[mi], bfr[ni], acc[mi][ni], 0, 0, 0);
            }
            __syncthreads();
        }

        // fused FiLM epilogue: ni 0=sk, 1=bs, 2=gs for the SAME column c
        const int c  = (2 * jt2 + wn) * 16 + lr;
        const int rb = (l >> 4) << 2;
        #pragma unroll
        for (int mi = 0; mi < 4; ++mi)
            #pragma unroll
            for (int j = 0; j < 4; ++j) {
                long node = node0 + wm * 64 + mi * 16 + rb + j;
                if (node < N_NODES) {
                    float o = fmaxf(acc[mi][2][j] * acc[mi][0][j] + acc[mi][1][j], 0.f);
                    skbh[node * 128 + c] = __float2bfloat16(o);
                }
            }
    }
}

// ---------------------------------------------------------------------------
// Aggregation v3: 1 wave per node; lane owns 4 cols (uint2 = 8 B gather);
// half-waves process two edges per gather instruction; 4 pairs unrolled
// (8 edges in flight). 32-bit offsets. Cross-half shfl_xor(32) reduction.
// ---------------------------------------------------------------------------
__global__ __launch_bounds__(256) void agg_kernel(
    const uint2* __restrict__ h22,      // hbuf  as [N][32] uint2
    const uint2* __restrict__ bgu2,     // bgbuf as [N][64] uint2 (beta 0..31 | gamma 32..63)
    const int* __restrict__ row_ptr, const int* __restrict__ csr_src,
    const float* __restrict__ deg_inv,
    const uint2* __restrict__ sku2,     // skb as [N][32] uint2 (bf16, relu'd)
    uint2* __restrict__ An2,            // next A as [N][32] uint2 (bf16)
    float4* __restrict__ fo4)           // final out as [N][32] float4
{
    const int t = threadIdx.x;
    const int v = blockIdx.x * 4 + (t >> 6);
    const int l = t & 63;
    const int half = l >> 5;
    const unsigned c = l & 31;

    const uint2 bu = bgu2[(size_t)v * 64 + c];
    const uint2 gu = bgu2[(size_t)v * 64 + 32 + c];
    const float2 be01 = bf2f(bu.x), be23 = bf2f(bu.y);
    const float2 ga01 = bf2f(gu.x), ga23 = bf2f(gu.y);
    const float dinv = deg_inv[v];

    const int b = row_ptr[v];
    const int e = row_ptr[v + 1];
    const int ne = e - b;
    const int npair = ne >> 1;

    f32x4 ac0 = {0,0,0,0}, ac1 = {0,0,0,0}, ac2 = {0,0,0,0}, ac3 = {0,0,0,0};

    const int* cp = csr_src + b + half;   // this lane's edge stream (stride 2)

#define ACC(A_, P_) do {                                   \
        float2 h01 = bf2f((P_).x), h23 = bf2f((P_).y);     \
        (A_)[0] += fmaxf(ga01.x * h01.x + be01.x, 0.f);    \
        (A_)[1] += fmaxf(ga01.y * h01.y + be01.y, 0.f);    \
        (A_)[2] += fmaxf(ga23.x * h23.x + be23.x, 0.f);    \
        (A_)[3] += fmaxf(ga23.y * h23.y + be23.y, 0.f);    \
    } while (0)

    int pi = 0;
    for (; pi + 4 <= npair; pi += 4) {
        const int i0 = 2 * pi;
        const unsigned s0 = (unsigned)cp[i0];
        const unsigned s1 = (unsigned)cp[i0 + 2];
        const unsigned s2 = (unsigned)cp[i0 + 4];
        const unsigned s3 = (unsigned)cp[i0 + 6];
        const uint2 p0 = h22[s0 * 32u + c];
        const uint2 p1 = h22[s1 * 32u + c];
        const uint2 p2 = h22[s2 * 32u + c];
        const uint2 p3 = h22[s3 * 32u + c];
        ACC(ac0, p0); ACC(ac1, p1); ACC(ac2, p2); ACC(ac3, p3);
    }
    for (; pi < npair; ++pi) {
        const unsigned s0 = (unsigned)cp[2 * pi];
        const uint2 p0 = h22[s0 * 32u + c];
        ACC(ac0, p0);
    }
    if ((ne & 1) && half == 0) {
        const unsigned s0 = (unsigned)csr_src[e - 1];
        const uint2 p0 = h22[s0 * 32u + c];
        ACC(ac1, p0);
    }
#undef ACC

    float r0 = (ac0[0] + ac1[0]) + (ac2[0] + ac3[0]);
    float r1 = (ac0[1] + ac1[1]) + (ac2[1] + ac3[1]);
    float r2 = (ac0[2] + ac1[2]) + (ac2[2] + ac3[2]);
    float r3 = (ac0[3] + ac1[3]) + (ac2[3] + ac3[3]);
    r0 += __shfl_xor(r0, 32);
    r1 += __shfl_xor(r1, 32);
    r2 += __shfl_xor(r2, 32);
    r3 += __shfl_xor(r3, 32);

    const uint2 sk = sku2[(size_t)v * 32 + c];
    const float2 s01 = bf2f(sk.x), s23 = bf2f(sk.y);
    const float o0 = s01.x + r0 * dinv;
    const float o1 = s01.y + r1 * dinv;
    const float o2 = s23.x + r2 * dinv;
    const float o3 = s23.y + r3 * dinv;

    if (half == 0) {
        if (An2) {
            An2[(size_t)v * 32 + c] = make_uint2(f2bf2(o0, o1), f2bf2(o2, o3));
        } else {
            fo4[(size_t)v * 32 + c] = make_float4(o0, o1, o2, o3);
        }
    }
}

// ---------------------------------------------------------------------------
extern "C" void kernel_launch(void* const* d_in, const int* in_sizes, int n_in,
                              void* d_out, int out_size, void* d_ws, size_t ws_size,
                              hipStream_t stream) {
    const float*    x_in    = (const float*)d_in[0];
    const unsigned* eidx    = (const unsigned*)d_in[1];
    const float*    W_lin   = (const float*)d_in[2];
    const float*    W_film  = (const float*)d_in[3];
    const float*    b_film  = (const float*)d_in[4];
    const float*    W_skip  = (const float*)d_in[5];
    const float*    W_fskip = (const float*)d_in[6];
    float*          out     = (float*)d_out;

    char* ws = (char*)d_ws;
    size_t off = 0;
    auto alloc = [&](size_t bytes) -> void* {
        void* p = ws + off;
        off = (off + bytes + 255) & ~(size_t)255;
        return p;
    };
    int*   flag      = (int*)alloc(4);
    int*   counts    = (int*)alloc((size_t)N_NODES * 4);
    int*   row_ptr   = (int*)alloc((size_t)(N_NODES + 1) * 4);
    int*   cursor    = (int*)alloc((size_t)N_NODES * 4);
    int*   blockSums = (int*)alloc(128 * 4);
    float* deg_inv   = (float*)alloc((size_t)N_NODES * 4);
    int*   csr_src   = (int*)alloc((size_t)N_EDGES * 4);
    __hip_bfloat16* Abuf  = (__hip_bfloat16*)alloc((size_t)N_PAD * 128 * 2);
    __hip_bfloat16* BtAll = (__hip_bfloat16*)alloc((size_t)4 * 768 * 128 * 2);
    __hip_bfloat16* hbuf  = (__hip_bfloat16*)alloc((size_t)N_NODES * 128 * 2);
    __hip_bfloat16* bgbuf = (__hip_bfloat16*)alloc((size_t)N_NODES * 256 * 2);
    __hip_bfloat16* skbh  = (__hip_bfloat16*)alloc((size_t)N_NODES * 128 * 2);
    (void)ws_size; (void)in_sizes; (void)n_in; (void)out_size;

    const int NB_SCAN = (N_NODES + 1023) / 1024; // 98
    const int EB = (N_EDGES + 255) / 256;        // 6250

    hipMemsetAsync(counts, 0, (size_t)N_NODES * 4, stream);
    detect_kernel<<<1, 256, 0, stream>>>(eidx, flag);
    hist_kernel<<<EB, 256, 0, stream>>>(eidx, flag, counts);
    scan1_kernel<<<NB_SCAN, 256, 0, stream>>>(counts, blockSums);
    scan2_kernel<<<1, 1, 0, stream>>>(blockSums, NB_SCAN, row_ptr);
    scan3_kernel<<<NB_SCAN, 256, 0, stream>>>(counts, blockSums, row_ptr, cursor, deg_inv);
    fill2_kernel<<<NXCD * NSLICE, 256, 0, stream>>>(eidx, flag, cursor, csr_src);

    cast_kernel<<<(N_NODES * 64 + 255) / 256, 256, 0, stream>>>(x_in, (unsigned*)Abuf);
    bt_prep_kernel<<<(4 * 768 * 128 + 255) / 256, 256, 0, stream>>>(
        W_lin, W_film, W_skip, W_fskip, BtAll);

    const int MT = N_PAD / 128; // 782
    const int AGG_B = N_NODES / 4; // 25000
    for (int l = 0; l < 4; ++l) {
        const __hip_bfloat16* Bt_l = BtAll + (size_t)l * 768 * 128;
        fused_gemm_kernel<<<MT * 7, 256, 0, stream>>>(
            Abuf, Bt_l, b_film + (size_t)l * 256, hbuf, bgbuf, skbh);
        agg_kernel<<<AGG_B, 256, 0, stream>>>(
            (const uint2*)hbuf, (const uint2*)bgbuf,
            row_ptr, csr_src, deg_inv, (const uint2*)skbh,
            (l < 3) ? (uint2*)Abuf : (uint2*)nullptr,
            (l == 3) ? (float4*)out : (float4*)nullptr);
    }
}